// Round 10
// baseline (553.073 us; speedup 1.0000x reference)
//
#include <hip/hip_runtime.h>
#include <hip/hip_bf16.h>
#include <math.h>

typedef __hip_bfloat16 bf16;
typedef __attribute__((ext_vector_type(8))) short short8_t;
typedef __attribute__((ext_vector_type(4))) short short4_t;
typedef __attribute__((ext_vector_type(4))) float f32x4_t;

#define EPSV 1e-5f
#define BNSC 0.99999500003749968f  // 1/sqrt(1+1e-5)

__device__ __forceinline__ float bf2f(bf16 v){ return __bfloat162float(v); }
__device__ __forceinline__ bf16 f2bf(float v){ return __float2bfloat16(v); }

__device__ __forceinline__ float blk_sum(float v, float* sm){
  int tid = threadIdx.x;
  #pragma unroll
  for(int o=32;o>0;o>>=1) v += __shfl_down(v, o, 64);
  if((tid&63)==0) sm[tid>>6] = v;
  __syncthreads();
  float s = 0.f;
  int nw = blockDim.x>>6;
  for(int i=0;i<nw;i++) s += sm[i];
  __syncthreads();
  return s;
}

__device__ __forceinline__ float softplusf(float x){
  return (x > 20.f) ? x : __logf(1.f + __expf(x));
}
__device__ __forceinline__ float siluf(float x){
  return x / (1.f + __expf(-x));
}

// one-shot prep: 4 bf16 converts + proj transpose + zero stat accumulators
__global__ void prep_weights(const float* __restrict__ in_w, const float* __restrict__ out_w,
                             const float* __restrict__ pw_w, const float* __restrict__ dpw_w,
                             const float* __restrict__ proj_w,
                             bf16* __restrict__ Winb, bf16* __restrict__ Woutb,
                             bf16* __restrict__ Wub, bf16* __restrict__ Wdb,
                             float* __restrict__ PT, float* __restrict__ gacc){
  int idx = blockIdx.x*256 + threadIdx.x;      // < 1,048,576
  if(idx < 1536) gacc[idx] = 0.f;
  if(idx < 524288){ Winb[idx] = f2bf(in_w[idx]); return; }
  if(idx < 786432){ int i=idx-524288; Woutb[i] = f2bf(out_w[i]); return; }
  if(idx < 851968){ int i=idx-786432; Wub[i] = f2bf(pw_w[i]); return; }
  if(idx < 917504){ int i=idx-851968; Wdb[i] = f2bf(dpw_w[i]); return; }
  int k = idx - 917504;                        // < 131072
  int i = k >> 9, j = k & 511;
  PT[j*256 + i] = proj_w[k];
}

// R1: per (b,c) slice: col max/min over h, row max/min over w, + pos-emb + idx
__global__ void r1_reduce_pe(const float* __restrict__ x, const float* __restrict__ pe,
                             float* __restrict__ pmax, float* __restrict__ pmin){
  __shared__ float tile[64*65];
  int bc = blockIdx.x;          // b*256 + c
  int b = bc >> 8, c = bc & 255;
  const float* xp = x + ((size_t)bc << 12);
  for(int i=threadIdx.x; i<4096; i+=64)
    tile[(i>>6)*65 + (i&63)] = xp[i];
  __syncthreads();
  int t = threadIdx.x;
  float cmx=-3.4e38f, cmn=3.4e38f; int cax=0, can=0;
  for(int h=0;h<64;h++){
    float v = tile[h*65 + t];
    if(v > cmx){ cmx=v; cax=h; }
    if(v < cmn){ cmn=v; can=h; }
  }
  float rmx=-3.4e38f, rmn=3.4e38f; int rax=0, ran=0;
  for(int w=0;w<64;w++){
    float v = tile[t*65 + w];
    if(v > rmx){ rmx=v; rax=w; }
    if(v < rmn){ rmn=v; ran=w; }
  }
  float coords = fmaxf((t + 0.5f)*0.25f - 0.5f, 0.f);
  int i0 = (int)floorf(coords);
  int i1 = min(i0+1, 15);
  float wg = coords - (float)i0;
  float pos = pe[c*16+i0]*(1.f-wg) + pe[c*16+i1]*wg;
  size_t base_col = ((size_t)b*128 + t)*256 + c;
  size_t base_row = ((size_t)b*128 + 64 + t)*256 + c;
  pmax[base_col] = cmx + pos + (float)cax;
  pmin[base_col] = cmn + pos + (float)can;
  pmax[base_row] = rmx + pos + (float)rax;
  pmin[base_row] = rmn + pos + (float)ran;
}

// paired LN over 256: rows<1024 -> A, else B; writes f32 back + bf16 copy
__global__ void ln_rows2(float* __restrict__ bufA, float* __restrict__ bufB,
                         const float* __restrict__ g, const float* __restrict__ bb,
                         bf16* __restrict__ boutA, bf16* __restrict__ boutB){
  __shared__ float sm[8];
  int row = blockIdx.x, t = threadIdx.x;
  float* buf; bf16* bout;
  if(row < 1024){ buf = bufA; bout = boutA; }
  else { buf = bufB; bout = boutB; row -= 1024; }
  float v = buf[(size_t)row*256 + t];
  float m = blk_sum(v, sm) * (1.f/256.f);
  float dv = v - m;
  float var = blk_sum(dv*dv, sm) * (1.f/256.f);
  float r = dv * rsqrtf(var + EPSV) * g[t] + bb[t];
  buf[(size_t)row*256 + t] = r;
  if(bout) bout[(size_t)row*256 + t] = f2bf(r);
}

// M1 (MFMA): xz[rb][l][i] = sum_c u_bf(b,l_eff,c) * in_w_bf[d][i][c]
__global__ __launch_bounds__(256,2)
void m1_mfma(const bf16* __restrict__ ubmax, const bf16* __restrict__ ubmin,
             const bf16* __restrict__ Win, float* __restrict__ xz){
  __shared__ bf16 att[64*264];
  int bx = blockIdx.x;
  int it = bx & 3, lt = (bx>>2)&1, b = (bx>>3)&7, r = bx>>6;
  int d = r & 1;
  const bf16* u = (r < 2) ? ubmax : ubmin;
  int flip = r & 1;
  int t = threadIdx.x;
  {
    int pr = t>>5, cc = (t&31)*8;
    #pragma unroll
    for(int i=0;i<8;i++){
      int p = pr + i*8;
      int l = lt*64 + p;
      int le = flip ? (127 - l) : l;
      short8_t v = *(const short8_t*)((const short*)u + ((size_t)(b*128 + le))*256 + cc);
      *(short8_t*)&att[p*264 + cc] = v;
    }
  }
  __syncthreads();
  int wv = t>>6, lane = t&63, quad = lane>>4, l16 = lane&15;
  int m0 = wv*64;
  f32x4_t acc[4][4];
  #pragma unroll
  for(int ms=0;ms<4;ms++)
    #pragma unroll
    for(int ns=0;ns<4;ns++) acc[ms][ns] = (f32x4_t){0.f,0.f,0.f,0.f};
  const short* wbase = (const short*)Win + ((size_t)d*1024 + it*256)*256;
  for(int k0=0;k0<256;k0+=32){
    short8_t afr[4], bfr[4];
    #pragma unroll
    for(int ms=0;ms<4;ms++)
      afr[ms] = *(const short8_t*)(wbase + (size_t)(m0 + ms*16 + l16)*256 + k0 + quad*8);
    #pragma unroll
    for(int ns=0;ns<4;ns++)
      bfr[ns] = *(const short8_t*)&att[(ns*16 + l16)*264 + k0 + quad*8];
    #pragma unroll
    for(int ms=0;ms<4;ms++)
      #pragma unroll
      for(int ns=0;ns<4;ns++)
        acc[ms][ns] = __builtin_amdgcn_mfma_f32_16x16x32_bf16(afr[ms], bfr[ns], acc[ms][ns], 0,0,0);
  }
  int rb = r*8 + b;
  #pragma unroll
  for(int ns=0;ns<4;ns++){
    int l = lt*64 + ns*16 + l16;
    float* dst = xz + ((size_t)rb*128 + l)*1024 + it*256;
    #pragma unroll
    for(int ms=0;ms<4;ms++){
      int i = m0 + ms*16 + quad*4;
      *(f32x4_t*)(dst + i) = acc[ms][ns];
    }
  }
}

// M234: per (rb,l) row: conv+silu -> xc ; xproj -> dbl ; dt -> softplus
__global__ __launch_bounds__(256)
void m234(const float* __restrict__ xz, const float* __restrict__ cw,
          const float* __restrict__ cb, const float* __restrict__ xproj,
          const float* __restrict__ dtw, const float* __restrict__ dtbias,
          float* __restrict__ xc, float* __restrict__ dbl, float* __restrict__ dt){
  __shared__ float xzs[4*512];
  __shared__ float xcs[512];
  __shared__ float pbuf[192];
  __shared__ float dblrow[48];
  int rowid = blockIdx.x;           // rb*128 + l
  int rb = rowid >> 7, l = rowid & 127;
  int d = (rb >> 3) & 1;
  int t = threadIdx.x;
  #pragma unroll
  for(int i=0;i<8;i++){
    int idx = t + i*256;            // < 2048
    int r = idx >> 9, dd = idx & 511;
    int ls = l - 3 + r;
    xzs[idx] = (ls >= 0) ? xz[((size_t)rb*128 + ls)*1024 + dd] : 0.f;
  }
  __syncthreads();
  #pragma unroll
  for(int i=0;i<2;i++){
    int dd = t + i*256;
    const float* w = cw + (size_t)(d*512 + dd)*4;
    float s = cb[d*512 + dd];
    #pragma unroll
    for(int k=0;k<4;k++) s += xzs[k*512 + dd] * w[k];
    s = siluf(s);
    xcs[dd] = s;
    xc[(size_t)rowid*512 + dd] = s;
  }
  __syncthreads();
  if(t < 192){
    int e = t >> 2, part = t & 3;
    const float* wp = xproj + (size_t)(d*48 + e)*512 + part*128;
    const float* xr = xcs + part*128;
    float s = 0.f;
    for(int k=0;k<128;k++) s += xr[k]*wp[k];
    pbuf[t] = s;
  }
  __syncthreads();
  if(t < 48){
    float s = pbuf[t*4] + pbuf[t*4+1] + pbuf[t*4+2] + pbuf[t*4+3];
    dblrow[t] = s;
    dbl[(size_t)rowid*48 + t] = s;
  }
  __syncthreads();
  #pragma unroll
  for(int i=0;i<2;i++){
    int dd = t + i*256;
    const float* wp = dtw + (size_t)(d*512 + dd)*16;
    float s = dtbias[d*512 + dd];
    #pragma unroll
    for(int r=0;r<16;r++) s += dblrow[r]*wp[r];
    dt[(size_t)rowid*512 + dd] = softplusf(s);
  }
}

// M5a: chunked scan pass A
__global__ void m5_passA(const float* __restrict__ dt, const float* __restrict__ xc,
                         const float* __restrict__ dbl, const float* __restrict__ Alog,
                         float* __restrict__ P, float* __restrict__ Hl){
  int bx = blockIdx.x;
  int seg = bx & 7, half = (bx>>3)&1, rb = bx>>4;
  int dd = half*256 + threadIdx.x;
  int d = (rb>>3)&1;
  float A[16], h[16], pr[16];
  #pragma unroll
  for(int s=0;s<16;s++){
    A[s] = -__expf(Alog[(size_t)(d*512 + dd)*16 + s]);
    h[s] = 0.f; pr[s] = 1.f;
  }
  int l0 = seg*16;
  for(int l=l0;l<l0+16;l++){
    size_t row = (size_t)rb*128 + l;
    float dtv = dt[row*512 + dd];
    float xcv = xc[row*512 + dd];
    float bx_ = dtv*xcv;
    const float* dr = dbl + row*48;
    #pragma unroll
    for(int s=0;s<16;s++){
      float dA = __expf(dtv*A[s]);
      pr[s] *= dA;
      h[s] = dA*h[s] + bx_*dr[16+s];
    }
  }
  size_t o = ((size_t)(rb*8 + seg)*512 + dd)*16;
  #pragma unroll
  for(int s=0;s<16;s+=4){
    *(f32x4_t*)(P  + o + s) = (f32x4_t){pr[s],pr[s+1],pr[s+2],pr[s+3]};
    *(f32x4_t*)(Hl + o + s) = (f32x4_t){h[s],h[s+1],h[s+2],h[s+3]};
  }
}

// M5b: combine prefix, re-scan, emit y
__global__ void m5_passB(const float* __restrict__ dt, const float* __restrict__ xc,
                         const float* __restrict__ dbl, const float* __restrict__ xz,
                         const float* __restrict__ Alog, const float* __restrict__ Dp,
                         const float* __restrict__ P, const float* __restrict__ Hl,
                         bf16* __restrict__ ybb){
  int bx = blockIdx.x;
  int seg = bx & 7, half = (bx>>3)&1, rb = bx>>4;
  int dd = half*256 + threadIdx.x;
  int d = (rb>>3)&1;
  float A[16], h[16];
  #pragma unroll
  for(int s=0;s<16;s++){
    A[s] = -__expf(Alog[(size_t)(d*512 + dd)*16 + s]);
    h[s] = 0.f;
  }
  for(int j=0;j<seg;j++){
    size_t o = ((size_t)(rb*8 + j)*512 + dd)*16;
    #pragma unroll
    for(int s=0;s<16;s+=4){
      f32x4_t pv = *(const f32x4_t*)(P + o + s);
      f32x4_t hv = *(const f32x4_t*)(Hl + o + s);
      h[s]   = pv[0]*h[s]   + hv[0];
      h[s+1] = pv[1]*h[s+1] + hv[1];
      h[s+2] = pv[2]*h[s+2] + hv[2];
      h[s+3] = pv[3]*h[s+3] + hv[3];
    }
  }
  float Dv = Dp[d*512 + dd];
  int l0 = seg*16;
  for(int l=l0;l<l0+16;l++){
    size_t row = (size_t)rb*128 + l;
    float dtv = dt[row*512 + dd];
    float xcv = xc[row*512 + dd];
    float zgv = xz[row*1024 + 512 + dd];
    const float* dr = dbl + row*48;
    float bx_ = dtv*xcv;
    float y = 0.f;
    #pragma unroll
    for(int s=0;s<16;s++){
      h[s] = __expf(dtv*A[s])*h[s] + bx_*dr[16+s];
      y += h[s]*dr[32+s];
    }
    ybb[row*512 + dd] = f2bf((y + xcv*Dv) * siluf(zgv));
  }
}

// M6 (MFMA) + fused row-LN
__global__ __launch_bounds__(256,2)
void m6_mfma(const bf16* __restrict__ ybb, const bf16* __restrict__ Wout,
             const float* __restrict__ lng, const float* __restrict__ lnb,
             float* __restrict__ mo){
  __shared__ char smem[64*264*4];
  bf16* ybt = (bf16*)smem;
  float* fbuf = (float*)smem;
  int bx = blockIdx.x;
  int lt = bx & 1, b = (bx>>1)&7, r = bx>>4;
  int d = r & 1, rb = r*8 + b;
  size_t rowbase = (size_t)rb*128 + lt*64;
  int t = threadIdx.x;
  for(int i=t;i<4096;i+=256){
    int row = i>>6, c8 = (i&63)*8;
    short8_t v = *(const short8_t*)((const short*)ybb + (rowbase + row)*512 + c8);
    *(short8_t*)&ybt[row*520 + c8] = v;
  }
  __syncthreads();
  int wv = t>>6, lane = t&63, quad = lane>>4, l16 = lane&15;
  int m0 = wv*64;
  f32x4_t acc[4][4];
  #pragma unroll
  for(int ms=0;ms<4;ms++)
    #pragma unroll
    for(int ns=0;ns<4;ns++) acc[ms][ns] = (f32x4_t){0.f,0.f,0.f,0.f};
  const short* wbase = (const short*)Wout + (size_t)d*256*512;
  for(int k0=0;k0<512;k0+=32){
    short8_t afr[4], bfr[4];
    #pragma unroll
    for(int ms=0;ms<4;ms++)
      afr[ms] = *(const short8_t*)(wbase + (size_t)(m0 + ms*16 + l16)*512 + k0 + quad*8);
    #pragma unroll
    for(int ns=0;ns<4;ns++)
      bfr[ns] = *(const short8_t*)&ybt[(ns*16 + l16)*520 + k0 + quad*8];
    #pragma unroll
    for(int ms=0;ms<4;ms++)
      #pragma unroll
      for(int ns=0;ns<4;ns++)
        acc[ms][ns] = __builtin_amdgcn_mfma_f32_16x16x32_bf16(afr[ms], bfr[ns], acc[ms][ns], 0,0,0);
  }
  __syncthreads();
  #pragma unroll
  for(int ns=0;ns<4;ns++){
    int row = ns*16 + l16;
    #pragma unroll
    for(int ms=0;ms<4;ms++){
      int o = m0 + ms*16 + quad*4;
      *(f32x4_t*)(fbuf + row*264 + o) = acc[ms][ns];
    }
  }
  __syncthreads();
  {
    int row = t >> 2, part = t & 3;
    const float* fr = fbuf + row*264;
    float s = 0.f;
    #pragma unroll 8
    for(int j=0;j<64;j++){
      int col = part*64 + ((j + part*16) & 63);
      s += fr[col];
    }
    s += __shfl_xor(s, 1, 64);
    s += __shfl_xor(s, 2, 64);
    float m = s * (1.f/256.f);
    float q = 0.f;
    #pragma unroll 8
    for(int j=0;j<64;j++){
      int col = part*64 + ((j + part*16) & 63);
      float dv = fr[col] - m;
      q += dv*dv;
    }
    q += __shfl_xor(q, 1, 64);
    q += __shfl_xor(q, 2, 64);
    float rs = rsqrtf(q*(1.f/256.f) + EPSV);
    float* dst = mo + (rowbase + row)*256;
    for(int j=0;j<64;j++){
      int col = part*64 + j;
      dst[col] = (fr[col] - m)*rs*lng[col] + lnb[col];
    }
  }
}

// M7 + fused row-LN on outputs
__global__ void m7_proj(const float* __restrict__ mo, const float* __restrict__ PT,
                        const float* __restrict__ pb, const float* __restrict__ lng,
                        const float* __restrict__ lnb, float* __restrict__ resm,
                        float* __restrict__ resn){
  __shared__ float ct[16*512];
  __shared__ float fbuf[16*264];
  int bx = blockIdx.x;
  int tt = bx >> 6, rem = bx & 63, b = rem >> 3, lt = rem & 7;
  int fr_ = tt*2, br = tt*2 + 1;
  for(int i=threadIdx.x;i<16*512;i+=256){
    int lr = i >> 9, k = i & 511;
    int l = lt*16 + lr;
    ct[i] = (k < 256)
      ? mo[(((size_t)(fr_*8+b)*128) + l)*256 + k]
      : mo[(((size_t)(br*8+b)*128) + (127-l))*256 + (k-256)];
  }
  __syncthreads();
  float acc[16];
  #pragma unroll
  for(int q=0;q<16;q++) acc[q] = 0.f;
  int t = threadIdx.x;
  for(int k=0;k<512;k++){
    float pv = PT[(size_t)k*256 + t];
    #pragma unroll
    for(int q=0;q<16;q++) acc[q] += pv * ct[(q<<9) + k];
  }
  float bias = pb[t];
  #pragma unroll
  for(int q=0;q<16;q++) fbuf[q*264 + t] = acc[q] + bias;
  __syncthreads();
  float* dstbuf = tt ? resn : resm;
  if(t < 64){
    int row = t >> 2, part = t & 3;
    const float* fr = fbuf + row*264;
    float s = 0.f;
    for(int j=0;j<64;j++){
      int col = part*64 + ((j + part*16) & 63);
      s += fr[col];
    }
    s += __shfl_xor(s, 1, 64);
    s += __shfl_xor(s, 2, 64);
    float m = s * (1.f/256.f);
    float q = 0.f;
    for(int j=0;j<64;j++){
      int col = part*64 + ((j + part*16) & 63);
      float dv = fr[col] - m;
      q += dv*dv;
    }
    q += __shfl_xor(q, 1, 64);
    q += __shfl_xor(q, 2, 64);
    float rs = rsqrtf(q*(1.f/256.f) + EPSV);
    float* dst = dstbuf + ((size_t)b*128 + lt*16 + row)*256;
    for(int j=0;j<64;j++){
      int col = part*64 + j;
      dst[col] = (fr[col] - m)*rs*lng[col] + lnb[col];
    }
  }
}

// K1: stride-2 transposed depthwise 3x3 + BN + ReLU -> zT (pixel-major bf16)
__global__ __launch_bounds__(256)
void k1_deconv_T(const float* __restrict__ x, const float* __restrict__ wdw,
                 const float* __restrict__ g1, const float* __restrict__ b1,
                 bf16* __restrict__ zT){
  __shared__ float in[2*64*33];
  __shared__ bf16 ot[64*80];
  int bx = blockIdx.x;
  int cb = bx & 3, half = (bx>>2)&1, h = (bx>>3)&127, b = bx>>10;
  int c0 = cb*64, w0 = half*64, iw0 = w0>>1;
  int h_odd = h & 1;
  int ihA = h_odd ? (h-1)>>1 : h>>1;
  int ihB = (h+1)>>1;
  bool hasB = h_odd && (ihB < 64);
  for(int i = threadIdx.x; i < 4224; i += 256){
    int row = i / 2112;
    int rem = i - row*2112;
    int c = rem / 33;
    int iw = rem - c*33;
    int ihl = row ? ihB : ihA;
    bool valid = (iw0 + iw < 64) && (row == 0 || hasB);
    in[i] = valid ? x[(((size_t)b*256 + c0 + c)<<12) + (ihl<<6) + iw0 + iw] : 0.f;
  }
  __syncthreads();
  int c = threadIdx.x & 63, g = threadIdx.x >> 6;
  const float* wp = wdw + (c0+c)*9;
  int khA3 = h_odd ? 6 : 3;
  float wA0 = wp[khA3], wA1 = wp[khA3+1], wA2 = wp[khA3+2];
  float wB0 = wp[0],    wB1 = wp[1],      wB2 = wp[2];
  float scale = g1[c0+c]*BNSC, bias = b1[c0+c];
  const float* inA = in + c*33;
  const float* inB = in + 2112 + c*33;
  #pragma unroll
  for(int i=0;i<16;i++){
    int wi = g*16 + i;
    float s;
    if(!(i&1)){
      int iw = wi>>1;
      s = inA[iw]*wA1 + inB[iw]*wB1;
    } else {
      int iwa = (wi-1)>>1, iwb = (wi+1)>>1;
      s = inA[iwa]*wA2 + inA[iwb]*wA0 + inB[iwa]*wB2 + inB[iwb]*wB0;
    }
    ot[wi*80 + c] = f2bf(fmaxf(s*scale + bias, 0.f));
  }
  __syncthreads();
  int rr = threadIdx.x >> 3;
  int co = (threadIdx.x & 7) * 8;
  size_t obase = (((size_t)b*16384) + (size_t)h*128 + w0)*256 + c0;
  #pragma unroll
  for(int pass=0; pass<2; pass++){
    int wi = rr + pass*32;
    short8_t v = *(const short8_t*)&ot[wi*80 + co];
    *(short8_t*)((short*)zT + obase + (size_t)wi*256 + co) = v;
  }
}

// K2 (MFMA): 128 px x 256 out, K=256, prefetch weights + GN1 stats via shfl
__global__ __launch_bounds__(256,2)
void k2_mfma(const bf16* __restrict__ zT, const bf16* __restrict__ Wub,
             const float* __restrict__ g2, const float* __restrict__ b2,
             const float* __restrict__ resm, const float* __restrict__ resn,
             bf16* __restrict__ resT, float* __restrict__ gsum, float* __restrict__ gssq){
  __shared__ bf16 zt[128*264];
  int b = blockIdx.y;
  int p0 = blockIdx.x*128;
  int t = threadIdx.x;
  {
    const short* src = (const short*)zT + (((size_t)b*16384 + p0)*256);
    int pr = t>>5;
    int cc = (t&31)*8;
    #pragma unroll
    for(int i=0;i<16;i++){
      int p = pr + i*8;
      short8_t v = *(const short8_t*)(src + (size_t)p*256 + cc);
      *(short8_t*)&zt[p*264 + cc] = v;
    }
  }
  __syncthreads();
  int wv = t>>6, lane = t&63, quad = lane>>4, l16 = lane&15;
  int m0 = wv*64;
  f32x4_t acc[4][8];
  #pragma unroll
  for(int ms=0;ms<4;ms++)
    #pragma unroll
    for(int ns=0;ns<8;ns++) acc[ms][ns] = (f32x4_t){0.f,0.f,0.f,0.f};
  const short* wp = (const short*)Wub + (size_t)(m0 + l16)*256 + quad*8;
  short8_t afr[4];
  #pragma unroll
  for(int ms=0;ms<4;ms++) afr[ms] = *(const short8_t*)(wp + (size_t)ms*16*256);
  for(int k0=0;k0<256;k0+=32){
    short8_t anext[4];
    if(k0 + 32 < 256){
      #pragma unroll
      for(int ms=0;ms<4;ms++)
        anext[ms] = *(const short8_t*)(wp + (size_t)ms*16*256 + k0 + 32);
    }
    short8_t bfr[8];
    #pragma unroll
    for(int ns=0;ns<8;ns++)
      bfr[ns] = *(const short8_t*)&zt[(ns*16 + l16)*264 + k0 + quad*8];
    #pragma unroll
    for(int ms=0;ms<4;ms++)
      #pragma unroll
      for(int ns=0;ns<8;ns++)
        acc[ms][ns] = __builtin_amdgcn_mfma_f32_16x16x32_bf16(afr[ms], bfr[ns], acc[ms][ns], 0,0,0);
    #pragma unroll
    for(int ms=0;ms<4;ms++) afr[ms] = anext[ms];
  }
  float sm_[4] = {0.f,0.f,0.f,0.f}, sq_[4] = {0.f,0.f,0.f,0.f};
  #pragma unroll
  for(int ns=0;ns<8;ns++){
    int p = p0 + ns*16 + l16;
    int hh = p>>7, ww = p&127;
    const float* rm = resm + ((size_t)b*128+hh)*256;
    const float* rn = resn + ((size_t)b*128+ww)*256;
    size_t orow = ((size_t)b*16384 + p)*256;
    #pragma unroll
    for(int ms=0;ms<4;ms++){
      int o = m0 + ms*16 + quad*4;
      f32x4_t a = acc[ms][ns];
      f32x4_t gv = *(const f32x4_t*)(g2+o);
      f32x4_t bv = *(const f32x4_t*)(b2+o);
      f32x4_t rmv = *(const f32x4_t*)(rm+o);
      f32x4_t rnv = *(const f32x4_t*)(rn+o);
      alignas(8) bf16 ov[4];
      #pragma unroll
      for(int r=0;r<4;r++){
        float zv = a[r]*(gv[r]*BNSC) + bv[r];
        zv = fminf(fmaxf(zv, 0.f), 6.f);
        float gate = fminf(fmaxf(rmv[r]+rnv[r]+3.f, 0.f), 6.f)*(1.f/6.f);
        float val = zv*gate;
        sm_[ms] += val;
        sq_[ms] += val*val;
        ov[r] = f2bf(val);
      }
      *(short4_t*)((short*)resT + orow + o) = *(const short4_t*)ov;
    }
  }
  // GN1 stats: half-wave (32 lanes) shares group ((m0+ms*16)>>3)+(quad>>1)
  #pragma unroll
  for(int ms=0;ms<4;ms++){
    float S = sm_[ms], Q = sq_[ms];
    #pragma unroll
    for(int o=1;o<=16;o<<=1){
      S += __shfl_xor(S, o, 32);
      Q += __shfl_xor(Q, o, 32);
    }
    if((lane & 31) == 0){
      int g = ((m0 + ms*16) >> 3) + (quad >> 1);
      atomicAdd(&gsum[b*32 + g], S);
      atomicAdd(&gssq[b*32 + g], Q);
    }
  }
}

// K4 (MFMA): inline GN1 finalize, 128-px tile, weight prefetch, GN2 stats via shfl
__global__ __launch_bounds__(256,2)
void k4_mfma(const bf16* __restrict__ resT, const bf16* __restrict__ Wdb,
             const float* __restrict__ gsum1, const float* __restrict__ gssq1,
             const float* __restrict__ gng, const float* __restrict__ gnb,
             const float* __restrict__ dbg, const float* __restrict__ dbb,
             float* __restrict__ t1, float* __restrict__ gsum2, float* __restrict__ gssq2){
  __shared__ bf16 at[128*264];
  __shared__ float sc[256], sb[256];
  __shared__ float stm[32], str[32];
  int b = blockIdx.y;
  int q0 = blockIdx.x*128;
  int t = threadIdx.x;
  if(t < 32){
    float m = gsum1[b*32+t] * (1.f/131072.f);
    float var = gssq1[b*32+t] * (1.f/131072.f) - m*m;
    stm[t] = m;
    str[t] = rsqrtf(var + EPSV);
  }
  __syncthreads();
  {
    int cch = t, g = cch>>3;
    float m = stm[g], rs = str[g];
    float s = rs*gng[cch];
    sc[cch] = s; sb[cch] = gnb[cch] - m*s;
  }
  __syncthreads();
  {
    int pr = t>>5;
    int cc = (t&31)*8;
    #pragma unroll
    for(int i=0;i<16;i++){
      int q = pr + i*8;
      int qq = q0 + q;
      int y = qq>>6, xw = qq&63;
      size_t srow = ((size_t)b*16384 + (size_t)y*256 + xw*2)*256;
      short8_t v = *(const short8_t*)((const short*)resT + srow + cc);
      const bf16* vv = (const bf16*)&v;
      alignas(16) bf16 ov[8];
      #pragma unroll
      for(int j=0;j<8;j++) ov[j] = f2bf(bf2f(vv[j])*sc[cc+j] + sb[cc+j]);
      *(short8_t*)&at[q*264 + cc] = *(const short8_t*)ov;
    }
  }
  __syncthreads();
  int wv = t>>6, lane = t&63, quad = lane>>4, l16 = lane&15;
  int n0 = wv*64;
  f32x4_t acc[8][4];
  #pragma unroll
  for(int ms=0;ms<8;ms++)
    #pragma unroll
    for(int ns=0;ns<4;ns++) acc[ms][ns] = (f32x4_t){0.f,0.f,0.f,0.f};
  const short* wp = (const short*)Wdb + (size_t)(n0 + l16)*256 + quad*8;
  short8_t bfr[4];
  #pragma unroll
  for(int ns=0;ns<4;ns++) bfr[ns] = *(const short8_t*)(wp + (size_t)ns*16*256);
  for(int k0=0;k0<256;k0+=32){
    short8_t bnext[4];
    if(k0 + 32 < 256){
      #pragma unroll
      for(int ns=0;ns<4;ns++)
        bnext[ns] = *(const short8_t*)(wp + (size_t)ns*16*256 + k0 + 32);
    }
    short8_t afr[8];
    #pragma unroll
    for(int ms=0;ms<8;ms++)
      afr[ms] = *(const short8_t*)&at[(ms*16 + l16)*264 + k0 + quad*8];
    #pragma unroll
    for(int ms=0;ms<8;ms++)
      #pragma unroll
      for(int ns=0;ns<4;ns++)
        acc[ms][ns] = __builtin_amdgcn_mfma_f32_16x16x32_bf16(afr[ms], bfr[ns], acc[ms][ns], 0,0,0);
    #pragma unroll
    for(int ns=0;ns<4;ns++) bfr[ns] = bnext[ns];
  }
  #pragma unroll
  for(int ns=0;ns<4;ns++){
    int o = n0 + ns*16 + l16;
    float s2 = dbg[o]*BNSC, bb2 = dbb[o];
    float* dst = t1 + (((size_t)b*256 + o) << 12);
    float s_=0.f, q_=0.f;
    #pragma unroll
    for(int ms=0;ms<8;ms++){
      int ps = q0 + ms*16 + quad*4;
      f32x4_t a = acc[ms][ns];
      f32x4_t ov;
      #pragma unroll
      for(int r=0;r<4;r++){
        ov[r] = a[r]*s2 + bb2;
        s_ += ov[r];
        q_ += ov[r]*ov[r];
      }
      *(f32x4_t*)(dst + ps) = ov;
    }
    // GN2 stats: o depends only on l16; groups of 8 l16 values x 4 quads share o>>3
    #pragma unroll
    for(int msk=1; msk<=4; msk<<=1){
      s_ += __shfl_xor(s_, msk, 64);
      q_ += __shfl_xor(q_, msk, 64);
    }
    s_ += __shfl_xor(s_, 16, 64);
    q_ += __shfl_xor(q_, 16, 64);
    s_ += __shfl_xor(s_, 32, 64);
    q_ += __shfl_xor(q_, 32, 64);
    if(((l16 & 7) == 0) && (quad == 0)){
      atomicAdd(&gsum2[b*32 + (o>>3)], s_);
      atomicAdd(&gssq2[b*32 + (o>>3)], q_);
    }
  }
}

// K6 (float4): t1 = gn2(t1) + x, + GN3 partials
__global__ void k6_gn_add(float* __restrict__ t1, const float* __restrict__ x,
                          const float* __restrict__ gsum2, const float* __restrict__ gssq2,
                          const float* __restrict__ gng, const float* __restrict__ gnb,
                          float* __restrict__ gsum3, float* __restrict__ gssq3){
  __shared__ float sm[8];
  int i4 = blockIdx.x*256 + threadIdx.x;
  int idx = i4 << 2;
  int c = (idx >> 12) & 255, b = idx >> 20, g = c >> 3;
  float m2 = gsum2[b*32+g] * (1.f/32768.f);
  float var = gssq2[b*32+g] * (1.f/32768.f) - m2*m2;
  float rs = rsqrtf(var + EPSV);
  float scl = rs*gng[c], off = gnb[c] - m2*scl;
  f32x4_t tv = *(const f32x4_t*)(t1 + idx);
  f32x4_t xv = *(const f32x4_t*)(x + idx);
  f32x4_t ov;
  float S = 0.f, Q = 0.f;
  #pragma unroll
  for(int r=0;r<4;r++){
    float v = tv[r]*scl + off + xv[r];
    ov[r] = v;
    S += v; Q += v*v;
  }
  *(f32x4_t*)(t1 + idx) = ov;
  S = blk_sum(S, sm);
  Q = blk_sum(Q, sm);
  if(threadIdx.x == 0){
    atomicAdd(&gsum3[b*32 + g], S);
    atomicAdd(&gssq3[b*32 + g], Q);
  }
}

// K8 (float4): out = gn3(t1)
__global__ void k8_gn_out(const float* __restrict__ t1, const float* __restrict__ gsum3,
                          const float* __restrict__ gssq3, const float* __restrict__ gng,
                          const float* __restrict__ gnb, float* __restrict__ out){
  int i4 = blockIdx.x*256 + threadIdx.x;
  int idx = i4 << 2;
  int c = (idx >> 12) & 255, b = idx >> 20, g = c >> 3;
  float m = gsum3[b*32+g] * (1.f/32768.f);
  float var = gssq3[b*32+g] * (1.f/32768.f) - m*m;
  float rs = rsqrtf(var + EPSV);
  float scl = rs*gng[c], off = gnb[c] - m*scl;
  f32x4_t tv = *(const f32x4_t*)(t1 + idx);
  f32x4_t ov;
  #pragma unroll
  for(int r=0;r<4;r++) ov[r] = tv[r]*scl + off;
  *(f32x4_t*)(out + idx) = ov;
}

extern "C" void kernel_launch(void* const* d_in, const int* in_sizes, int n_in,
                              void* d_out, int out_size, void* d_ws, size_t ws_size,
                              hipStream_t stream){
  const float* x      = (const float*)d_in[0];
  const float* pos    = (const float*)d_in[1];
  const float* ln_g   = (const float*)d_in[2];
  const float* ln_b   = (const float*)d_in[3];
  const float* in_w   = (const float*)d_in[4];
  const float* conv_w = (const float*)d_in[5];
  const float* conv_b = (const float*)d_in[6];
  const float* xproj  = (const float*)d_in[7];
  const float* dt_w   = (const float*)d_in[8];
  const float* dt_b   = (const float*)d_in[9];
  const float* A_log  = (const float*)d_in[10];
  const float* Dp     = (const float*)d_in[11];
  const float* out_w  = (const float*)d_in[12];
  const float* proj_w = (const float*)d_in[13];
  const float* proj_b = (const float*)d_in[14];
  const float* dw_w   = (const float*)d_in[15];
  const float* bn1g   = (const float*)d_in[16];
  const float* bn1b   = (const float*)d_in[17];
  const float* pw_w   = (const float*)d_in[18];
  const float* bn2g   = (const float*)d_in[19];
  const float* bn2b   = (const float*)d_in[20];
  const float* dpw_w  = (const float*)d_in[21];
  const float* dbng   = (const float*)d_in[22];
  const float* dbnb   = (const float*)d_in[23];
  const float* gng    = (const float*)d_in[24];
  const float* gnb    = (const float*)d_in[25];
  float* out = (float*)d_out;

  float* ws = (float*)d_ws;
  bf16*  resT = (bf16*)ws;                       // pixel-major (b,p,c), 64MB
  bf16*  zT   = (bf16*)(ws + 16777216);          // pixel-major (b,p,c), 64MB
  float* scanP = ws + 16777216;                  // overlay of zT region
  float* scanH = ws + 16777216 + 2097152;
  float* zone = ws + 33554432;
  float* xz   = zone;                            // 4,194,304
  float* xc   = xz  + 4194304;                   // 2,097,152
  float* dbl  = xc  + 2097152;                   //   196,608
  float* dtb  = dbl + 196608;                    // 2,097,152
  bf16*  ybb  = (bf16*)(dtb + 2097152);          // 1,048,576 f worth
  float* t1   = zone;                            // overlay (first 8,388,608)
  float* mo   = zone + 9633792;                  // 1,048,576
  float* resm = mo   + 1048576;
  float* resn = resm + 262144;
  float* pmax = resn + 262144;
  float* pmin = pmax + 262144;
  float* PT   = pmin + 262144;
  bf16*  ubmax= (bf16*)(PT + 131072);
  bf16*  ubmin= (bf16*)(PT + 131072 + 131072);
  bf16*  Winb = (bf16*)(PT + 131072 + 262144);
  bf16*  Woutb= (bf16*)(PT + 131072 + 524288);
  bf16*  Wub  = (bf16*)(PT + 131072 + 655360);
  bf16*  Wdb  = (bf16*)(PT + 131072 + 688128);
  float* gacc = PT + 131072 + 720896;
  float* gsum1 = gacc,        *gssq1 = gacc + 256;
  float* gsum2 = gacc + 512,  *gssq2 = gacc + 768;
  float* gsum3 = gacc + 1024, *gssq3 = gacc + 1280;

  prep_weights<<<4096,256,0,stream>>>(in_w, out_w, pw_w, dpw_w, proj_w,
                                      Winb, Woutb, Wub, Wdb, PT, gacc);

  r1_reduce_pe<<<2048,64,0,stream>>>(x, pos, pmax, pmin);
  ln_rows2<<<2048,256,0,stream>>>(pmax, pmin, ln_g, ln_b, ubmax, ubmin);

  m1_mfma<<<256,256,0,stream>>>(ubmax, ubmin, Winb, xz);
  m234<<<4096,256,0,stream>>>(xz, conv_w, conv_b, xproj, dt_w, dt_b, xc, dbl, dtb);
  m5_passA<<<512,256,0,stream>>>(dtb, xc, dbl, A_log, scanP, scanH);
  m5_passB<<<512,256,0,stream>>>(dtb, xc, dbl, xz, A_log, Dp, scanP, scanH, ybb);
  m6_mfma<<<64,256,0,stream>>>(ybb, Woutb, ln_g, ln_b, mo);
  m7_proj<<<128,256,0,stream>>>(mo, PT, proj_b, ln_g, ln_b, resm, resn);

  k1_deconv_T<<<8192,256,0,stream>>>(x, dw_w, bn1g, bn1b, zT);
  k2_mfma<<<dim3(128,8),256,0,stream>>>(zT, Wub, bn2g, bn2b, resm, resn,
                                        resT, gsum1, gssq1);

  k4_mfma<<<dim3(32,8),256,0,stream>>>(resT, Wdb, gsum1, gssq1,
                                       gng, gnb, dbng, dbnb, t1, gsum2, gssq2);

  k6_gn_add<<<8192,256,0,stream>>>(t1, x, gsum2, gssq2, gng, gnb, gsum3, gssq3);
  k8_gn_out<<<8192,256,0,stream>>>(t1, gsum3, gssq3, gng, gnb, out);
}

// Round 11
// 547.357 us; speedup vs baseline: 1.0104x; 1.0104x over previous
//
#include <hip/hip_runtime.h>
#include <hip/hip_bf16.h>
#include <math.h>

typedef __hip_bfloat16 bf16;
typedef __attribute__((ext_vector_type(8))) short short8_t;
typedef __attribute__((ext_vector_type(4))) short short4_t;
typedef __attribute__((ext_vector_type(4))) float f32x4_t;

#define EPSV 1e-5f
#define BNSC 0.99999500003749968f  // 1/sqrt(1+1e-5)

__device__ __forceinline__ float bf2f(bf16 v){ return __bfloat162float(v); }
__device__ __forceinline__ bf16 f2bf(float v){ return __float2bfloat16(v); }

__device__ __forceinline__ float blk_sum(float v, float* sm){
  int tid = threadIdx.x;
  #pragma unroll
  for(int o=32;o>0;o>>=1) v += __shfl_down(v, o, 64);
  if((tid&63)==0) sm[tid>>6] = v;
  __syncthreads();
  float s = 0.f;
  int nw = blockDim.x>>6;
  for(int i=0;i<nw;i++) s += sm[i];
  __syncthreads();
  return s;
}

__device__ __forceinline__ float softplusf(float x){
  return (x > 20.f) ? x : __logf(1.f + __expf(x));
}
__device__ __forceinline__ float siluf(float x){
  return x / (1.f + __expf(-x));
}

// one-shot prep: 4 bf16 converts + proj transpose + zero stat accumulators
__global__ void prep_weights(const float* __restrict__ in_w, const float* __restrict__ out_w,
                             const float* __restrict__ pw_w, const float* __restrict__ dpw_w,
                             const float* __restrict__ proj_w,
                             bf16* __restrict__ Winb, bf16* __restrict__ Woutb,
                             bf16* __restrict__ Wub, bf16* __restrict__ Wdb,
                             float* __restrict__ PT, float* __restrict__ gacc){
  int idx = blockIdx.x*256 + threadIdx.x;      // < 1,048,576
  if(idx < 1536) gacc[idx] = 0.f;
  if(idx < 524288){ Winb[idx] = f2bf(in_w[idx]); return; }
  if(idx < 786432){ int i=idx-524288; Woutb[i] = f2bf(out_w[i]); return; }
  if(idx < 851968){ int i=idx-786432; Wub[i] = f2bf(pw_w[i]); return; }
  if(idx < 917504){ int i=idx-851968; Wdb[i] = f2bf(dpw_w[i]); return; }
  int k = idx - 917504;                        // < 131072
  int i = k >> 9, j = k & 511;
  PT[j*256 + i] = proj_w[k];
}

// R1: per (b,c) slice: col max/min over h, row max/min over w, + pos-emb + idx
__global__ void r1_reduce_pe(const float* __restrict__ x, const float* __restrict__ pe,
                             float* __restrict__ pmax, float* __restrict__ pmin){
  __shared__ float tile[64*65];
  int bc = blockIdx.x;          // b*256 + c
  int b = bc >> 8, c = bc & 255;
  const float* xp = x + ((size_t)bc << 12);
  for(int i=threadIdx.x; i<4096; i+=64)
    tile[(i>>6)*65 + (i&63)] = xp[i];
  __syncthreads();
  int t = threadIdx.x;
  float cmx=-3.4e38f, cmn=3.4e38f; int cax=0, can=0;
  for(int h=0;h<64;h++){
    float v = tile[h*65 + t];
    if(v > cmx){ cmx=v; cax=h; }
    if(v < cmn){ cmn=v; can=h; }
  }
  float rmx=-3.4e38f, rmn=3.4e38f; int rax=0, ran=0;
  for(int w=0;w<64;w++){
    float v = tile[t*65 + w];
    if(v > rmx){ rmx=v; rax=w; }
    if(v < rmn){ rmn=v; ran=w; }
  }
  float coords = fmaxf((t + 0.5f)*0.25f - 0.5f, 0.f);
  int i0 = (int)floorf(coords);
  int i1 = min(i0+1, 15);
  float wg = coords - (float)i0;
  float pos = pe[c*16+i0]*(1.f-wg) + pe[c*16+i1]*wg;
  size_t base_col = ((size_t)b*128 + t)*256 + c;
  size_t base_row = ((size_t)b*128 + 64 + t)*256 + c;
  pmax[base_col] = cmx + pos + (float)cax;
  pmin[base_col] = cmn + pos + (float)can;
  pmax[base_row] = rmx + pos + (float)rax;
  pmin[base_row] = rmn + pos + (float)ran;
}

// paired LN over 256: rows<1024 -> A, else B; writes f32 back + bf16 copy
__global__ void ln_rows2(float* __restrict__ bufA, float* __restrict__ bufB,
                         const float* __restrict__ g, const float* __restrict__ bb,
                         bf16* __restrict__ boutA, bf16* __restrict__ boutB){
  __shared__ float sm[8];
  int row = blockIdx.x, t = threadIdx.x;
  float* buf; bf16* bout;
  if(row < 1024){ buf = bufA; bout = boutA; }
  else { buf = bufB; bout = boutB; row -= 1024; }
  float v = buf[(size_t)row*256 + t];
  float m = blk_sum(v, sm) * (1.f/256.f);
  float dv = v - m;
  float var = blk_sum(dv*dv, sm) * (1.f/256.f);
  float r = dv * rsqrtf(var + EPSV) * g[t] + bb[t];
  buf[(size_t)row*256 + t] = r;
  if(bout) bout[(size_t)row*256 + t] = f2bf(r);
}

// M1 (MFMA): xz[rb][l][i] = sum_c u_bf(b,l_eff,c) * in_w_bf[d][i][c]
__global__ __launch_bounds__(256,2)
void m1_mfma(const bf16* __restrict__ ubmax, const bf16* __restrict__ ubmin,
             const bf16* __restrict__ Win, float* __restrict__ xz){
  __shared__ bf16 att[64*264];
  int bx = blockIdx.x;
  int it = bx & 3, lt = (bx>>2)&1, b = (bx>>3)&7, r = bx>>6;
  int d = r & 1;
  const bf16* u = (r < 2) ? ubmax : ubmin;
  int flip = r & 1;
  int t = threadIdx.x;
  {
    int pr = t>>5, cc = (t&31)*8;
    #pragma unroll
    for(int i=0;i<8;i++){
      int p = pr + i*8;
      int l = lt*64 + p;
      int le = flip ? (127 - l) : l;
      short8_t v = *(const short8_t*)((const short*)u + ((size_t)(b*128 + le))*256 + cc);
      *(short8_t*)&att[p*264 + cc] = v;
    }
  }
  __syncthreads();
  int wv = t>>6, lane = t&63, quad = lane>>4, l16 = lane&15;
  int m0 = wv*64;
  f32x4_t acc[4][4];
  #pragma unroll
  for(int ms=0;ms<4;ms++)
    #pragma unroll
    for(int ns=0;ns<4;ns++) acc[ms][ns] = (f32x4_t){0.f,0.f,0.f,0.f};
  const short* wbase = (const short*)Win + ((size_t)d*1024 + it*256)*256;
  for(int k0=0;k0<256;k0+=32){
    short8_t afr[4], bfr[4];
    #pragma unroll
    for(int ms=0;ms<4;ms++)
      afr[ms] = *(const short8_t*)(wbase + (size_t)(m0 + ms*16 + l16)*256 + k0 + quad*8);
    #pragma unroll
    for(int ns=0;ns<4;ns++)
      bfr[ns] = *(const short8_t*)&att[(ns*16 + l16)*264 + k0 + quad*8];
    #pragma unroll
    for(int ms=0;ms<4;ms++)
      #pragma unroll
      for(int ns=0;ns<4;ns++)
        acc[ms][ns] = __builtin_amdgcn_mfma_f32_16x16x32_bf16(afr[ms], bfr[ns], acc[ms][ns], 0,0,0);
  }
  int rb = r*8 + b;
  #pragma unroll
  for(int ns=0;ns<4;ns++){
    int l = lt*64 + ns*16 + l16;
    float* dst = xz + ((size_t)rb*128 + l)*1024 + it*256;
    #pragma unroll
    for(int ms=0;ms<4;ms++){
      int i = m0 + ms*16 + quad*4;
      *(f32x4_t*)(dst + i) = acc[ms][ns];
    }
  }
}

// M234: per (rb,l) row: conv+silu -> xc ; xproj -> dbl ; dt -> softplus
__global__ __launch_bounds__(256)
void m234(const float* __restrict__ xz, const float* __restrict__ cw,
          const float* __restrict__ cb, const float* __restrict__ xproj,
          const float* __restrict__ dtw, const float* __restrict__ dtbias,
          float* __restrict__ xc, float* __restrict__ dbl, float* __restrict__ dt){
  __shared__ float xzs[4*512];
  __shared__ float xcs[512];
  __shared__ float pbuf[192];
  __shared__ float dblrow[48];
  int rowid = blockIdx.x;           // rb*128 + l
  int rb = rowid >> 7, l = rowid & 127;
  int d = (rb >> 3) & 1;
  int t = threadIdx.x;
  #pragma unroll
  for(int i=0;i<8;i++){
    int idx = t + i*256;            // < 2048
    int r = idx >> 9, dd = idx & 511;
    int ls = l - 3 + r;
    xzs[idx] = (ls >= 0) ? xz[((size_t)rb*128 + ls)*1024 + dd] : 0.f;
  }
  __syncthreads();
  #pragma unroll
  for(int i=0;i<2;i++){
    int dd = t + i*256;
    const float* w = cw + (size_t)(d*512 + dd)*4;
    float s = cb[d*512 + dd];
    #pragma unroll
    for(int k=0;k<4;k++) s += xzs[k*512 + dd] * w[k];
    s = siluf(s);
    xcs[dd] = s;
    xc[(size_t)rowid*512 + dd] = s;
  }
  __syncthreads();
  if(t < 192){
    int e = t >> 2, part = t & 3;
    const float* wp = xproj + (size_t)(d*48 + e)*512 + part*128;
    const float* xr = xcs + part*128;
    float s = 0.f;
    for(int k=0;k<128;k++) s += xr[k]*wp[k];
    pbuf[t] = s;
  }
  __syncthreads();
  if(t < 48){
    float s = pbuf[t*4] + pbuf[t*4+1] + pbuf[t*4+2] + pbuf[t*4+3];
    dblrow[t] = s;
    dbl[(size_t)rowid*48 + t] = s;
  }
  __syncthreads();
  #pragma unroll
  for(int i=0;i<2;i++){
    int dd = t + i*256;
    const float* wp = dtw + (size_t)(d*512 + dd)*16;
    float s = dtbias[d*512 + dd];
    #pragma unroll
    for(int r=0;r<16;r++) s += dblrow[r]*wp[r];
    dt[(size_t)rowid*512 + dd] = softplusf(s);
  }
}

// M5a: chunked scan pass A
__global__ void m5_passA(const float* __restrict__ dt, const float* __restrict__ xc,
                         const float* __restrict__ dbl, const float* __restrict__ Alog,
                         float* __restrict__ P, float* __restrict__ Hl){
  int bx = blockIdx.x;
  int seg = bx & 7, half = (bx>>3)&1, rb = bx>>4;
  int dd = half*256 + threadIdx.x;
  int d = (rb>>3)&1;
  float A[16], h[16], pr[16];
  #pragma unroll
  for(int s=0;s<16;s++){
    A[s] = -__expf(Alog[(size_t)(d*512 + dd)*16 + s]);
    h[s] = 0.f; pr[s] = 1.f;
  }
  int l0 = seg*16;
  for(int l=l0;l<l0+16;l++){
    size_t row = (size_t)rb*128 + l;
    float dtv = dt[row*512 + dd];
    float xcv = xc[row*512 + dd];
    float bx_ = dtv*xcv;
    const float* dr = dbl + row*48;
    #pragma unroll
    for(int s=0;s<16;s++){
      float dA = __expf(dtv*A[s]);
      pr[s] *= dA;
      h[s] = dA*h[s] + bx_*dr[16+s];
    }
  }
  size_t o = ((size_t)(rb*8 + seg)*512 + dd)*16;
  #pragma unroll
  for(int s=0;s<16;s+=4){
    *(f32x4_t*)(P  + o + s) = (f32x4_t){pr[s],pr[s+1],pr[s+2],pr[s+3]};
    *(f32x4_t*)(Hl + o + s) = (f32x4_t){h[s],h[s+1],h[s+2],h[s+3]};
  }
}

// M5b: combine prefix, re-scan, emit y
__global__ void m5_passB(const float* __restrict__ dt, const float* __restrict__ xc,
                         const float* __restrict__ dbl, const float* __restrict__ xz,
                         const float* __restrict__ Alog, const float* __restrict__ Dp,
                         const float* __restrict__ P, const float* __restrict__ Hl,
                         bf16* __restrict__ ybb){
  int bx = blockIdx.x;
  int seg = bx & 7, half = (bx>>3)&1, rb = bx>>4;
  int dd = half*256 + threadIdx.x;
  int d = (rb>>3)&1;
  float A[16], h[16];
  #pragma unroll
  for(int s=0;s<16;s++){
    A[s] = -__expf(Alog[(size_t)(d*512 + dd)*16 + s]);
    h[s] = 0.f;
  }
  for(int j=0;j<seg;j++){
    size_t o = ((size_t)(rb*8 + j)*512 + dd)*16;
    #pragma unroll
    for(int s=0;s<16;s+=4){
      f32x4_t pv = *(const f32x4_t*)(P + o + s);
      f32x4_t hv = *(const f32x4_t*)(Hl + o + s);
      h[s]   = pv[0]*h[s]   + hv[0];
      h[s+1] = pv[1]*h[s+1] + hv[1];
      h[s+2] = pv[2]*h[s+2] + hv[2];
      h[s+3] = pv[3]*h[s+3] + hv[3];
    }
  }
  float Dv = Dp[d*512 + dd];
  int l0 = seg*16;
  for(int l=l0;l<l0+16;l++){
    size_t row = (size_t)rb*128 + l;
    float dtv = dt[row*512 + dd];
    float xcv = xc[row*512 + dd];
    float zgv = xz[row*1024 + 512 + dd];
    const float* dr = dbl + row*48;
    float bx_ = dtv*xcv;
    float y = 0.f;
    #pragma unroll
    for(int s=0;s<16;s++){
      h[s] = __expf(dtv*A[s])*h[s] + bx_*dr[16+s];
      y += h[s]*dr[32+s];
    }
    ybb[row*512 + dd] = f2bf((y + xcv*Dv) * siluf(zgv));
  }
}

// M6 (MFMA) + fused row-LN
__global__ __launch_bounds__(256,2)
void m6_mfma(const bf16* __restrict__ ybb, const bf16* __restrict__ Wout,
             const float* __restrict__ lng, const float* __restrict__ lnb,
             float* __restrict__ mo){
  __shared__ char smem[64*264*4];
  bf16* ybt = (bf16*)smem;
  float* fbuf = (float*)smem;
  int bx = blockIdx.x;
  int lt = bx & 1, b = (bx>>1)&7, r = bx>>4;
  int d = r & 1, rb = r*8 + b;
  size_t rowbase = (size_t)rb*128 + lt*64;
  int t = threadIdx.x;
  for(int i=t;i<4096;i+=256){
    int row = i>>6, c8 = (i&63)*8;
    short8_t v = *(const short8_t*)((const short*)ybb + (rowbase + row)*512 + c8);
    *(short8_t*)&ybt[row*520 + c8] = v;
  }
  __syncthreads();
  int wv = t>>6, lane = t&63, quad = lane>>4, l16 = lane&15;
  int m0 = wv*64;
  f32x4_t acc[4][4];
  #pragma unroll
  for(int ms=0;ms<4;ms++)
    #pragma unroll
    for(int ns=0;ns<4;ns++) acc[ms][ns] = (f32x4_t){0.f,0.f,0.f,0.f};
  const short* wbase = (const short*)Wout + (size_t)d*256*512;
  for(int k0=0;k0<512;k0+=32){
    short8_t afr[4], bfr[4];
    #pragma unroll
    for(int ms=0;ms<4;ms++)
      afr[ms] = *(const short8_t*)(wbase + (size_t)(m0 + ms*16 + l16)*512 + k0 + quad*8);
    #pragma unroll
    for(int ns=0;ns<4;ns++)
      bfr[ns] = *(const short8_t*)&ybt[(ns*16 + l16)*520 + k0 + quad*8];
    #pragma unroll
    for(int ms=0;ms<4;ms++)
      #pragma unroll
      for(int ns=0;ns<4;ns++)
        acc[ms][ns] = __builtin_amdgcn_mfma_f32_16x16x32_bf16(afr[ms], bfr[ns], acc[ms][ns], 0,0,0);
  }
  __syncthreads();
  #pragma unroll
  for(int ns=0;ns<4;ns++){
    int row = ns*16 + l16;
    #pragma unroll
    for(int ms=0;ms<4;ms++){
      int o = m0 + ms*16 + quad*4;
      *(f32x4_t*)(fbuf + row*264 + o) = acc[ms][ns];
    }
  }
  __syncthreads();
  {
    int row = t >> 2, part = t & 3;
    const float* fr = fbuf + row*264;
    float s = 0.f;
    #pragma unroll 8
    for(int j=0;j<64;j++){
      int col = part*64 + ((j + part*16) & 63);
      s += fr[col];
    }
    s += __shfl_xor(s, 1, 64);
    s += __shfl_xor(s, 2, 64);
    float m = s * (1.f/256.f);
    float q = 0.f;
    #pragma unroll 8
    for(int j=0;j<64;j++){
      int col = part*64 + ((j + part*16) & 63);
      float dv = fr[col] - m;
      q += dv*dv;
    }
    q += __shfl_xor(q, 1, 64);
    q += __shfl_xor(q, 2, 64);
    float rs = rsqrtf(q*(1.f/256.f) + EPSV);
    float* dst = mo + (rowbase + row)*256;
    for(int j=0;j<64;j++){
      int col = part*64 + j;
      dst[col] = (fr[col] - m)*rs*lng[col] + lnb[col];
    }
  }
}

// M7 + fused row-LN on outputs
__global__ void m7_proj(const float* __restrict__ mo, const float* __restrict__ PT,
                        const float* __restrict__ pb, const float* __restrict__ lng,
                        const float* __restrict__ lnb, float* __restrict__ resm,
                        float* __restrict__ resn){
  __shared__ float ct[16*512];
  __shared__ float fbuf[16*264];
  int bx = blockIdx.x;
  int tt = bx >> 6, rem = bx & 63, b = rem >> 3, lt = rem & 7;
  int fr_ = tt*2, br = tt*2 + 1;
  for(int i=threadIdx.x;i<16*512;i+=256){
    int lr = i >> 9, k = i & 511;
    int l = lt*16 + lr;
    ct[i] = (k < 256)
      ? mo[(((size_t)(fr_*8+b)*128) + l)*256 + k]
      : mo[(((size_t)(br*8+b)*128) + (127-l))*256 + (k-256)];
  }
  __syncthreads();
  float acc[16];
  #pragma unroll
  for(int q=0;q<16;q++) acc[q] = 0.f;
  int t = threadIdx.x;
  for(int k=0;k<512;k++){
    float pv = PT[(size_t)k*256 + t];
    #pragma unroll
    for(int q=0;q<16;q++) acc[q] += pv * ct[(q<<9) + k];
  }
  float bias = pb[t];
  #pragma unroll
  for(int q=0;q<16;q++) fbuf[q*264 + t] = acc[q] + bias;
  __syncthreads();
  float* dstbuf = tt ? resn : resm;
  if(t < 64){
    int row = t >> 2, part = t & 3;
    const float* fr = fbuf + row*264;
    float s = 0.f;
    for(int j=0;j<64;j++){
      int col = part*64 + ((j + part*16) & 63);
      s += fr[col];
    }
    s += __shfl_xor(s, 1, 64);
    s += __shfl_xor(s, 2, 64);
    float m = s * (1.f/256.f);
    float q = 0.f;
    for(int j=0;j<64;j++){
      int col = part*64 + ((j + part*16) & 63);
      float dv = fr[col] - m;
      q += dv*dv;
    }
    q += __shfl_xor(q, 1, 64);
    q += __shfl_xor(q, 2, 64);
    float rs = rsqrtf(q*(1.f/256.f) + EPSV);
    float* dst = dstbuf + ((size_t)b*128 + lt*16 + row)*256;
    for(int j=0;j<64;j++){
      int col = part*64 + j;
      dst[col] = (fr[col] - m)*rs*lng[col] + lnb[col];
    }
  }
}

// K1: stride-2 transposed depthwise 3x3 + BN + ReLU -> zT (pixel-major bf16)
__global__ __launch_bounds__(256)
void k1_deconv_T(const float* __restrict__ x, const float* __restrict__ wdw,
                 const float* __restrict__ g1, const float* __restrict__ b1,
                 bf16* __restrict__ zT){
  __shared__ float in[2*64*33];
  __shared__ bf16 ot[64*80];
  int bx = blockIdx.x;
  int cb = bx & 3, half = (bx>>2)&1, h = (bx>>3)&127, b = bx>>10;
  int c0 = cb*64, w0 = half*64, iw0 = w0>>1;
  int h_odd = h & 1;
  int ihA = h_odd ? (h-1)>>1 : h>>1;
  int ihB = (h+1)>>1;
  bool hasB = h_odd && (ihB < 64);
  for(int i = threadIdx.x; i < 4224; i += 256){
    int row = i / 2112;
    int rem = i - row*2112;
    int c = rem / 33;
    int iw = rem - c*33;
    int ihl = row ? ihB : ihA;
    bool valid = (iw0 + iw < 64) && (row == 0 || hasB);
    in[i] = valid ? x[(((size_t)b*256 + c0 + c)<<12) + (ihl<<6) + iw0 + iw] : 0.f;
  }
  __syncthreads();
  int c = threadIdx.x & 63, g = threadIdx.x >> 6;
  const float* wp = wdw + (c0+c)*9;
  int khA3 = h_odd ? 6 : 3;
  float wA0 = wp[khA3], wA1 = wp[khA3+1], wA2 = wp[khA3+2];
  float wB0 = wp[0],    wB1 = wp[1],      wB2 = wp[2];
  float scale = g1[c0+c]*BNSC, bias = b1[c0+c];
  const float* inA = in + c*33;
  const float* inB = in + 2112 + c*33;
  #pragma unroll
  for(int i=0;i<16;i++){
    int wi = g*16 + i;
    float s;
    if(!(i&1)){
      int iw = wi>>1;
      s = inA[iw]*wA1 + inB[iw]*wB1;
    } else {
      int iwa = (wi-1)>>1, iwb = (wi+1)>>1;
      s = inA[iwa]*wA2 + inA[iwb]*wA0 + inB[iwa]*wB2 + inB[iwb]*wB0;
    }
    ot[wi*80 + c] = f2bf(fmaxf(s*scale + bias, 0.f));
  }
  __syncthreads();
  int rr = threadIdx.x >> 3;
  int co = (threadIdx.x & 7) * 8;
  size_t obase = (((size_t)b*16384) + (size_t)h*128 + w0)*256 + c0;
  #pragma unroll
  for(int pass=0; pass<2; pass++){
    int wi = rr + pass*32;
    short8_t v = *(const short8_t*)&ot[wi*80 + co];
    *(short8_t*)((short*)zT + obase + (size_t)wi*256 + co) = v;
  }
}

// K2 (MFMA): 128 px x 256 out, K=256, prefetch weights, NO fused stats (measured fastest)
__global__ __launch_bounds__(256,2)
void k2_mfma(const bf16* __restrict__ zT, const bf16* __restrict__ Wub,
             const float* __restrict__ g2, const float* __restrict__ b2,
             const float* __restrict__ resm, const float* __restrict__ resn,
             bf16* __restrict__ resT){
  __shared__ bf16 zt[128*264];
  int b = blockIdx.y;
  int p0 = blockIdx.x*128;
  int t = threadIdx.x;
  {
    const short* src = (const short*)zT + (((size_t)b*16384 + p0)*256);
    int pr = t>>5;
    int cc = (t&31)*8;
    #pragma unroll
    for(int i=0;i<16;i++){
      int p = pr + i*8;
      short8_t v = *(const short8_t*)(src + (size_t)p*256 + cc);
      *(short8_t*)&zt[p*264 + cc] = v;
    }
  }
  __syncthreads();
  int wv = t>>6, lane = t&63, quad = lane>>4, l16 = lane&15;
  int m0 = wv*64;
  f32x4_t acc[4][8];
  #pragma unroll
  for(int ms=0;ms<4;ms++)
    #pragma unroll
    for(int ns=0;ns<8;ns++) acc[ms][ns] = (f32x4_t){0.f,0.f,0.f,0.f};
  const short* wp = (const short*)Wub + (size_t)(m0 + l16)*256 + quad*8;
  short8_t afr[4];
  #pragma unroll
  for(int ms=0;ms<4;ms++) afr[ms] = *(const short8_t*)(wp + (size_t)ms*16*256);
  for(int k0=0;k0<256;k0+=32){
    short8_t anext[4];
    if(k0 + 32 < 256){
      #pragma unroll
      for(int ms=0;ms<4;ms++)
        anext[ms] = *(const short8_t*)(wp + (size_t)ms*16*256 + k0 + 32);
    }
    short8_t bfr[8];
    #pragma unroll
    for(int ns=0;ns<8;ns++)
      bfr[ns] = *(const short8_t*)&zt[(ns*16 + l16)*264 + k0 + quad*8];
    #pragma unroll
    for(int ms=0;ms<4;ms++)
      #pragma unroll
      for(int ns=0;ns<8;ns++)
        acc[ms][ns] = __builtin_amdgcn_mfma_f32_16x16x32_bf16(afr[ms], bfr[ns], acc[ms][ns], 0,0,0);
    #pragma unroll
    for(int ms=0;ms<4;ms++) afr[ms] = anext[ms];
  }
  #pragma unroll
  for(int ns=0;ns<8;ns++){
    int p = p0 + ns*16 + l16;
    int hh = p>>7, ww = p&127;
    const float* rm = resm + ((size_t)b*128+hh)*256;
    const float* rn = resn + ((size_t)b*128+ww)*256;
    size_t orow = ((size_t)b*16384 + p)*256;
    #pragma unroll
    for(int ms=0;ms<4;ms++){
      int o = m0 + ms*16 + quad*4;
      f32x4_t a = acc[ms][ns];
      f32x4_t gv = *(const f32x4_t*)(g2+o);
      f32x4_t bv = *(const f32x4_t*)(b2+o);
      f32x4_t rmv = *(const f32x4_t*)(rm+o);
      f32x4_t rnv = *(const f32x4_t*)(rn+o);
      alignas(8) bf16 ov[4];
      #pragma unroll
      for(int r=0;r<4;r++){
        float zv = a[r]*(gv[r]*BNSC) + bv[r];
        zv = fminf(fmaxf(zv, 0.f), 6.f);
        float gate = fminf(fmaxf(rmv[r]+rnv[r]+3.f, 0.f), 6.f)*(1.f/6.f);
        ov[r] = f2bf(zv*gate);
      }
      *(short4_t*)((short*)resT + orow + o) = *(const short4_t*)ov;
    }
  }
}

// GN1 stats over pixel-major resT (separate pass — measured cheaper than fusing)
__global__ void gn_stats_pm(const bf16* __restrict__ resT, float* __restrict__ sum,
                            float* __restrict__ ssq){
  __shared__ float ls[256], lq[256];
  int b = blockIdx.y, p0 = blockIdx.x*256;
  int c = threadIdx.x;
  const short* src = (const short*)resT + ((size_t)b*16384 + p0)*256 + c;
  float s=0.f, q=0.f;
  for(int i=0;i<256;i++){
    bf16 raw; *(short*)&raw = src[(size_t)i*256];
    float v = bf2f(raw);
    s += v; q += v*v;
  }
  ls[c]=s; lq[c]=q;
  __syncthreads();
  if(c<32){
    float S=0.f,Q=0.f;
    #pragma unroll
    for(int j=0;j<8;j++){ S+=ls[c*8+j]; Q+=lq[c*8+j]; }
    atomicAdd(&sum[b*32+c], S);
    atomicAdd(&ssq[b*32+c], Q);
  }
}

// K4 (MFMA): inline GN1 finalize, 128-px tile, weight prefetch, GN2 stats via shfl
__global__ __launch_bounds__(256,2)
void k4_mfma(const bf16* __restrict__ resT, const bf16* __restrict__ Wdb,
             const float* __restrict__ gsum1, const float* __restrict__ gssq1,
             const float* __restrict__ gng, const float* __restrict__ gnb,
             const float* __restrict__ dbg, const float* __restrict__ dbb,
             float* __restrict__ t1, float* __restrict__ gsum2, float* __restrict__ gssq2){
  __shared__ bf16 at[128*264];
  __shared__ float sc[256], sb[256];
  __shared__ float stm[32], str[32];
  int b = blockIdx.y;
  int q0 = blockIdx.x*128;
  int t = threadIdx.x;
  if(t < 32){
    float m = gsum1[b*32+t] * (1.f/131072.f);
    float var = gssq1[b*32+t] * (1.f/131072.f) - m*m;
    stm[t] = m;
    str[t] = rsqrtf(var + EPSV);
  }
  __syncthreads();
  {
    int cch = t, g = cch>>3;
    float m = stm[g], rs = str[g];
    float s = rs*gng[cch];
    sc[cch] = s; sb[cch] = gnb[cch] - m*s;
  }
  __syncthreads();
  {
    int pr = t>>5;
    int cc = (t&31)*8;
    #pragma unroll
    for(int i=0;i<16;i++){
      int q = pr + i*8;
      int qq = q0 + q;
      int y = qq>>6, xw = qq&63;
      size_t srow = ((size_t)b*16384 + (size_t)y*256 + xw*2)*256;
      short8_t v = *(const short8_t*)((const short*)resT + srow + cc);
      const bf16* vv = (const bf16*)&v;
      alignas(16) bf16 ov[8];
      #pragma unroll
      for(int j=0;j<8;j++) ov[j] = f2bf(bf2f(vv[j])*sc[cc+j] + sb[cc+j]);
      *(short8_t*)&at[q*264 + cc] = *(const short8_t*)ov;
    }
  }
  __syncthreads();
  int wv = t>>6, lane = t&63, quad = lane>>4, l16 = lane&15;
  int n0 = wv*64;
  f32x4_t acc[8][4];
  #pragma unroll
  for(int ms=0;ms<8;ms++)
    #pragma unroll
    for(int ns=0;ns<4;ns++) acc[ms][ns] = (f32x4_t){0.f,0.f,0.f,0.f};
  const short* wp = (const short*)Wdb + (size_t)(n0 + l16)*256 + quad*8;
  short8_t bfr[4];
  #pragma unroll
  for(int ns=0;ns<4;ns++) bfr[ns] = *(const short8_t*)(wp + (size_t)ns*16*256);
  for(int k0=0;k0<256;k0+=32){
    short8_t bnext[4];
    if(k0 + 32 < 256){
      #pragma unroll
      for(int ns=0;ns<4;ns++)
        bnext[ns] = *(const short8_t*)(wp + (size_t)ns*16*256 + k0 + 32);
    }
    short8_t afr[8];
    #pragma unroll
    for(int ms=0;ms<8;ms++)
      afr[ms] = *(const short8_t*)&at[(ms*16 + l16)*264 + k0 + quad*8];
    #pragma unroll
    for(int ms=0;ms<8;ms++)
      #pragma unroll
      for(int ns=0;ns<4;ns++)
        acc[ms][ns] = __builtin_amdgcn_mfma_f32_16x16x32_bf16(afr[ms], bfr[ns], acc[ms][ns], 0,0,0);
    #pragma unroll
    for(int ns=0;ns<4;ns++) bfr[ns] = bnext[ns];
  }
  #pragma unroll
  for(int ns=0;ns<4;ns++){
    int o = n0 + ns*16 + l16;
    float s2 = dbg[o]*BNSC, bb2 = dbb[o];
    float* dst = t1 + (((size_t)b*256 + o) << 12);
    float s_=0.f, q_=0.f;
    #pragma unroll
    for(int ms=0;ms<8;ms++){
      int ps = q0 + ms*16 + quad*4;
      f32x4_t a = acc[ms][ns];
      f32x4_t ov;
      #pragma unroll
      for(int r=0;r<4;r++){
        ov[r] = a[r]*s2 + bb2;
        s_ += ov[r];
        q_ += ov[r]*ov[r];
      }
      *(f32x4_t*)(dst + ps) = ov;
    }
    #pragma unroll
    for(int msk=1; msk<=4; msk<<=1){
      s_ += __shfl_xor(s_, msk, 64);
      q_ += __shfl_xor(q_, msk, 64);
    }
    s_ += __shfl_xor(s_, 16, 64);
    q_ += __shfl_xor(q_, 16, 64);
    s_ += __shfl_xor(s_, 32, 64);
    q_ += __shfl_xor(q_, 32, 64);
    if(((l16 & 7) == 0) && (quad == 0)){
      atomicAdd(&gsum2[b*32 + (o>>3)], s_);
      atomicAdd(&gssq2[b*32 + (o>>3)], q_);
    }
  }
}

// K6 (float4): t1 = gn2(t1) + x, + GN3 partials
__global__ void k6_gn_add(float* __restrict__ t1, const float* __restrict__ x,
                          const float* __restrict__ gsum2, const float* __restrict__ gssq2,
                          const float* __restrict__ gng, const float* __restrict__ gnb,
                          float* __restrict__ gsum3, float* __restrict__ gssq3){
  __shared__ float sm[8];
  int i4 = blockIdx.x*256 + threadIdx.x;
  int idx = i4 << 2;
  int c = (idx >> 12) & 255, b = idx >> 20, g = c >> 3;
  float m2 = gsum2[b*32+g] * (1.f/32768.f);
  float var = gssq2[b*32+g] * (1.f/32768.f) - m2*m2;
  float rs = rsqrtf(var + EPSV);
  float scl = rs*gng[c], off = gnb[c] - m2*scl;
  f32x4_t tv = *(const f32x4_t*)(t1 + idx);
  f32x4_t xv = *(const f32x4_t*)(x + idx);
  f32x4_t ov;
  float S = 0.f, Q = 0.f;
  #pragma unroll
  for(int r=0;r<4;r++){
    float v = tv[r]*scl + off + xv[r];
    ov[r] = v;
    S += v; Q += v*v;
  }
  *(f32x4_t*)(t1 + idx) = ov;
  S = blk_sum(S, sm);
  Q = blk_sum(Q, sm);
  if(threadIdx.x == 0){
    atomicAdd(&gsum3[b*32 + g], S);
    atomicAdd(&gssq3[b*32 + g], Q);
  }
}

// K8 (float4): out = gn3(t1)
__global__ void k8_gn_out(const float* __restrict__ t1, const float* __restrict__ gsum3,
                          const float* __restrict__ gssq3, const float* __restrict__ gng,
                          const float* __restrict__ gnb, float* __restrict__ out){
  int i4 = blockIdx.x*256 + threadIdx.x;
  int idx = i4 << 2;
  int c = (idx >> 12) & 255, b = idx >> 20, g = c >> 3;
  float m = gsum3[b*32+g] * (1.f/32768.f);
  float var = gssq3[b*32+g] * (1.f/32768.f) - m*m;
  float rs = rsqrtf(var + EPSV);
  float scl = rs*gng[c], off = gnb[c] - m*scl;
  f32x4_t tv = *(const f32x4_t*)(t1 + idx);
  f32x4_t ov;
  #pragma unroll
  for(int r=0;r<4;r++) ov[r] = tv[r]*scl + off;
  *(f32x4_t*)(out + idx) = ov;
}

extern "C" void kernel_launch(void* const* d_in, const int* in_sizes, int n_in,
                              void* d_out, int out_size, void* d_ws, size_t ws_size,
                              hipStream_t stream){
  const float* x      = (const float*)d_in[0];
  const float* pos    = (const float*)d_in[1];
  const float* ln_g   = (const float*)d_in[2];
  const float* ln_b   = (const float*)d_in[3];
  const float* in_w   = (const float*)d_in[4];
  const float* conv_w = (const float*)d_in[5];
  const float* conv_b = (const float*)d_in[6];
  const float* xproj  = (const float*)d_in[7];
  const float* dt_w   = (const float*)d_in[8];
  const float* dt_b   = (const float*)d_in[9];
  const float* A_log  = (const float*)d_in[10];
  const float* Dp     = (const float*)d_in[11];
  const float* out_w  = (const float*)d_in[12];
  const float* proj_w = (const float*)d_in[13];
  const float* proj_b = (const float*)d_in[14];
  const float* dw_w   = (const float*)d_in[15];
  const float* bn1g   = (const float*)d_in[16];
  const float* bn1b   = (const float*)d_in[17];
  const float* pw_w   = (const float*)d_in[18];
  const float* bn2g   = (const float*)d_in[19];
  const float* bn2b   = (const float*)d_in[20];
  const float* dpw_w  = (const float*)d_in[21];
  const float* dbng   = (const float*)d_in[22];
  const float* dbnb   = (const float*)d_in[23];
  const float* gng    = (const float*)d_in[24];
  const float* gnb    = (const float*)d_in[25];
  float* out = (float*)d_out;

  float* ws = (float*)d_ws;
  bf16*  resT = (bf16*)ws;                       // pixel-major (b,p,c), 64MB
  bf16*  zT   = (bf16*)(ws + 16777216);          // pixel-major (b,p,c), 64MB
  float* scanP = ws + 16777216;                  // overlay of zT region
  float* scanH = ws + 16777216 + 2097152;
  float* zone = ws + 33554432;
  float* xz   = zone;                            // 4,194,304
  float* xc   = xz  + 4194304;                   // 2,097,152
  float* dbl  = xc  + 2097152;                   //   196,608
  float* dtb  = dbl + 196608;                    // 2,097,152
  bf16*  ybb  = (bf16*)(dtb + 2097152);          // 1,048,576 f worth
  float* t1   = zone;                            // overlay (first 8,388,608)
  float* mo   = zone + 9633792;                  // 1,048,576
  float* resm = mo   + 1048576;
  float* resn = resm + 262144;
  float* pmax = resn + 262144;
  float* pmin = pmax + 262144;
  float* PT   = pmin + 262144;
  bf16*  ubmax= (bf16*)(PT + 131072);
  bf16*  ubmin= (bf16*)(PT + 131072 + 131072);
  bf16*  Winb = (bf16*)(PT + 131072 + 262144);
  bf16*  Woutb= (bf16*)(PT + 131072 + 524288);
  bf16*  Wub  = (bf16*)(PT + 131072 + 655360);
  bf16*  Wdb  = (bf16*)(PT + 131072 + 688128);
  float* gacc = PT + 131072 + 720896;
  float* gsum1 = gacc,        *gssq1 = gacc + 256;
  float* gsum2 = gacc + 512,  *gssq2 = gacc + 768;
  float* gsum3 = gacc + 1024, *gssq3 = gacc + 1280;

  prep_weights<<<4096,256,0,stream>>>(in_w, out_w, pw_w, dpw_w, proj_w,
                                      Winb, Woutb, Wub, Wdb, PT, gacc);

  r1_reduce_pe<<<2048,64,0,stream>>>(x, pos, pmax, pmin);
  ln_rows2<<<2048,256,0,stream>>>(pmax, pmin, ln_g, ln_b, ubmax, ubmin);

  m1_mfma<<<256,256,0,stream>>>(ubmax, ubmin, Winb, xz);
  m234<<<4096,256,0,stream>>>(xz, conv_w, conv_b, xproj, dt_w, dt_b, xc, dbl, dtb);
  m5_passA<<<512,256,0,stream>>>(dtb, xc, dbl, A_log, scanP, scanH);
  m5_passB<<<512,256,0,stream>>>(dtb, xc, dbl, xz, A_log, Dp, scanP, scanH, ybb);
  m6_mfma<<<64,256,0,stream>>>(ybb, Woutb, ln_g, ln_b, mo);
  m7_proj<<<128,256,0,stream>>>(mo, PT, proj_b, ln_g, ln_b, resm, resn);

  k1_deconv_T<<<8192,256,0,stream>>>(x, dw_w, bn1g, bn1b, zT);
  k2_mfma<<<dim3(128,8),256,0,stream>>>(zT, Wub, bn2g, bn2b, resm, resn, resT);
  gn_stats_pm<<<dim3(64,8),256,0,stream>>>(resT, gsum1, gssq1);

  k4_mfma<<<dim3(32,8),256,0,stream>>>(resT, Wdb, gsum1, gssq1,
                                       gng, gnb, dbng, dbnb, t1, gsum2, gssq2);

  k6_gn_add<<<8192,256,0,stream>>>(t1, x, gsum2, gssq2, gng, gnb, gsum3, gssq3);
  k8_gn_out<<<8192,256,0,stream>>>(t1, gsum3, gssq3, gng, gnb, out);
}

// Round 12
// 519.671 us; speedup vs baseline: 1.0643x; 1.0533x over previous
//
#include <hip/hip_runtime.h>
#include <hip/hip_bf16.h>
#include <math.h>

typedef __hip_bfloat16 bf16;
typedef __attribute__((ext_vector_type(8))) short short8_t;
typedef __attribute__((ext_vector_type(4))) short short4_t;
typedef __attribute__((ext_vector_type(4))) float f32x4_t;

#define EPSV 1e-5f
#define BNSC 0.99999500003749968f  // 1/sqrt(1+1e-5)

__device__ __forceinline__ float bf2f(bf16 v){ return __bfloat162float(v); }
__device__ __forceinline__ bf16 f2bf(float v){ return __float2bfloat16(v); }

__device__ __forceinline__ float blk_sum(float v, float* sm){
  int tid = threadIdx.x;
  #pragma unroll
  for(int o=32;o>0;o>>=1) v += __shfl_down(v, o, 64);
  if((tid&63)==0) sm[tid>>6] = v;
  __syncthreads();
  float s = 0.f;
  int nw = blockDim.x>>6;
  for(int i=0;i<nw;i++) s += sm[i];
  __syncthreads();
  return s;
}

__device__ __forceinline__ float softplusf(float x){
  return (x > 20.f) ? x : __logf(1.f + __expf(x));
}
__device__ __forceinline__ float siluf(float x){
  return x / (1.f + __expf(-x));
}

// one-shot prep: 4 bf16 converts + proj transpose + zero stat accumulators
__global__ void prep_weights(const float* __restrict__ in_w, const float* __restrict__ out_w,
                             const float* __restrict__ pw_w, const float* __restrict__ dpw_w,
                             const float* __restrict__ proj_w,
                             bf16* __restrict__ Winb, bf16* __restrict__ Woutb,
                             bf16* __restrict__ Wub, bf16* __restrict__ Wdb,
                             float* __restrict__ PT, float* __restrict__ gacc){
  int idx = blockIdx.x*256 + threadIdx.x;      // < 1,048,576
  if(idx < 1536) gacc[idx] = 0.f;
  if(idx < 524288){ Winb[idx] = f2bf(in_w[idx]); return; }
  if(idx < 786432){ int i=idx-524288; Woutb[i] = f2bf(out_w[i]); return; }
  if(idx < 851968){ int i=idx-786432; Wub[i] = f2bf(pw_w[i]); return; }
  if(idx < 917504){ int i=idx-851968; Wdb[i] = f2bf(dpw_w[i]); return; }
  int k = idx - 917504;                        // < 131072
  int i = k >> 9, j = k & 511;
  PT[j*256 + i] = proj_w[k];
}

// R1 (256 threads): load x slice coalesced; wave0 = col reduce, wave1 = row reduce
__global__ __launch_bounds__(256)
void r1_reduce_pe(const float* __restrict__ x, const float* __restrict__ pe,
                  float* __restrict__ pmax, float* __restrict__ pmin){
  __shared__ float tile[64*65];
  int bc = blockIdx.x;          // b*256 + c
  int b = bc >> 8, c = bc & 255;
  const float* xp = x + ((size_t)bc << 12);
  for(int i=threadIdx.x; i<4096; i+=256)
    tile[(i>>6)*65 + (i&63)] = xp[i];
  __syncthreads();
  int wv = threadIdx.x >> 6, t = threadIdx.x & 63;
  if(wv >= 2) return;
  float coords = fmaxf((t + 0.5f)*0.25f - 0.5f, 0.f);
  int i0 = (int)floorf(coords);
  int i1 = min(i0+1, 15);
  float wg = coords - (float)i0;
  float pos = pe[c*16+i0]*(1.f-wg) + pe[c*16+i1]*wg;
  if(wv == 0){
    float cmx=-3.4e38f, cmn=3.4e38f; int cax=0, can=0;
    for(int h=0;h<64;h++){
      float v = tile[h*65 + t];
      if(v > cmx){ cmx=v; cax=h; }
      if(v < cmn){ cmn=v; can=h; }
    }
    size_t base_col = ((size_t)b*128 + t)*256 + c;
    pmax[base_col] = cmx + pos + (float)cax;
    pmin[base_col] = cmn + pos + (float)can;
  } else {
    float rmx=-3.4e38f, rmn=3.4e38f; int rax=0, ran=0;
    for(int w=0;w<64;w++){
      float v = tile[t*65 + w];
      if(v > rmx){ rmx=v; rax=w; }
      if(v < rmn){ rmn=v; ran=w; }
    }
    size_t base_row = ((size_t)b*128 + 64 + t)*256 + c;
    pmax[base_row] = rmx + pos + (float)rax;
    pmin[base_row] = rmn + pos + (float)ran;
  }
}

// paired LN over 256: rows<1024 -> A, else B; writes f32 back + bf16 copy
__global__ void ln_rows2(float* __restrict__ bufA, float* __restrict__ bufB,
                         const float* __restrict__ g, const float* __restrict__ bb,
                         bf16* __restrict__ boutA, bf16* __restrict__ boutB){
  __shared__ float sm[8];
  int row = blockIdx.x, t = threadIdx.x;
  float* buf; bf16* bout;
  if(row < 1024){ buf = bufA; bout = boutA; }
  else { buf = bufB; bout = boutB; row -= 1024; }
  float v = buf[(size_t)row*256 + t];
  float m = blk_sum(v, sm) * (1.f/256.f);
  float dv = v - m;
  float var = blk_sum(dv*dv, sm) * (1.f/256.f);
  float r = dv * rsqrtf(var + EPSV) * g[t] + bb[t];
  buf[(size_t)row*256 + t] = r;
  if(bout) bout[(size_t)row*256 + t] = f2bf(r);
}

// M1 (MFMA): xz[rb][l][i] = sum_c u_bf(b,l_eff,c) * in_w_bf[d][i][c]
__global__ __launch_bounds__(256,2)
void m1_mfma(const bf16* __restrict__ ubmax, const bf16* __restrict__ ubmin,
             const bf16* __restrict__ Win, float* __restrict__ xz){
  __shared__ bf16 att[64*264];
  int bx = blockIdx.x;
  int it = bx & 3, lt = (bx>>2)&1, b = (bx>>3)&7, r = bx>>6;
  int d = r & 1;
  const bf16* u = (r < 2) ? ubmax : ubmin;
  int flip = r & 1;
  int t = threadIdx.x;
  {
    int pr = t>>5, cc = (t&31)*8;
    #pragma unroll
    for(int i=0;i<8;i++){
      int p = pr + i*8;
      int l = lt*64 + p;
      int le = flip ? (127 - l) : l;
      short8_t v = *(const short8_t*)((const short*)u + ((size_t)(b*128 + le))*256 + cc);
      *(short8_t*)&att[p*264 + cc] = v;
    }
  }
  __syncthreads();
  int wv = t>>6, lane = t&63, quad = lane>>4, l16 = lane&15;
  int m0 = wv*64;
  f32x4_t acc[4][4];
  #pragma unroll
  for(int ms=0;ms<4;ms++)
    #pragma unroll
    for(int ns=0;ns<4;ns++) acc[ms][ns] = (f32x4_t){0.f,0.f,0.f,0.f};
  const short* wbase = (const short*)Win + ((size_t)d*1024 + it*256)*256;
  for(int k0=0;k0<256;k0+=32){
    short8_t afr[4], bfr[4];
    #pragma unroll
    for(int ms=0;ms<4;ms++)
      afr[ms] = *(const short8_t*)(wbase + (size_t)(m0 + ms*16 + l16)*256 + k0 + quad*8);
    #pragma unroll
    for(int ns=0;ns<4;ns++)
      bfr[ns] = *(const short8_t*)&att[(ns*16 + l16)*264 + k0 + quad*8];
    #pragma unroll
    for(int ms=0;ms<4;ms++)
      #pragma unroll
      for(int ns=0;ns<4;ns++)
        acc[ms][ns] = __builtin_amdgcn_mfma_f32_16x16x32_bf16(afr[ms], bfr[ns], acc[ms][ns], 0,0,0);
  }
  int rb = r*8 + b;
  #pragma unroll
  for(int ns=0;ns<4;ns++){
    int l = lt*64 + ns*16 + l16;
    float* dst = xz + ((size_t)rb*128 + l)*1024 + it*256;
    #pragma unroll
    for(int ms=0;ms<4;ms++){
      int i = m0 + ms*16 + quad*4;
      *(f32x4_t*)(dst + i) = acc[ms][ns];
    }
  }
}

// M234: per (rb,l) row: conv+silu -> xc ; xproj -> dbl ; dt -> softplus
__global__ __launch_bounds__(256)
void m234(const float* __restrict__ xz, const float* __restrict__ cw,
          const float* __restrict__ cb, const float* __restrict__ xproj,
          const float* __restrict__ dtw, const float* __restrict__ dtbias,
          float* __restrict__ xc, float* __restrict__ dbl, float* __restrict__ dt){
  __shared__ float xzs[4*512];
  __shared__ float xcs[512];
  __shared__ float pbuf[192];
  __shared__ float dblrow[48];
  int rowid = blockIdx.x;           // rb*128 + l
  int rb = rowid >> 7, l = rowid & 127;
  int d = (rb >> 3) & 1;
  int t = threadIdx.x;
  #pragma unroll
  for(int i=0;i<8;i++){
    int idx = t + i*256;            // < 2048
    int r = idx >> 9, dd = idx & 511;
    int ls = l - 3 + r;
    xzs[idx] = (ls >= 0) ? xz[((size_t)rb*128 + ls)*1024 + dd] : 0.f;
  }
  __syncthreads();
  #pragma unroll
  for(int i=0;i<2;i++){
    int dd = t + i*256;
    const float* w = cw + (size_t)(d*512 + dd)*4;
    float s = cb[d*512 + dd];
    #pragma unroll
    for(int k=0;k<4;k++) s += xzs[k*512 + dd] * w[k];
    s = siluf(s);
    xcs[dd] = s;
    xc[(size_t)rowid*512 + dd] = s;
  }
  __syncthreads();
  if(t < 192){
    int e = t >> 2, part = t & 3;
    const float* wp = xproj + (size_t)(d*48 + e)*512 + part*128;
    const float* xr = xcs + part*128;
    float s = 0.f;
    for(int k=0;k<128;k++) s += xr[k]*wp[k];
    pbuf[t] = s;
  }
  __syncthreads();
  if(t < 48){
    float s = pbuf[t*4] + pbuf[t*4+1] + pbuf[t*4+2] + pbuf[t*4+3];
    dblrow[t] = s;
    dbl[(size_t)rowid*48 + t] = s;
  }
  __syncthreads();
  #pragma unroll
  for(int i=0;i<2;i++){
    int dd = t + i*256;
    const float* wp = dtw + (size_t)(d*512 + dd)*16;
    float s = dtbias[d*512 + dd];
    #pragma unroll
    for(int r=0;r<16;r++) s += dblrow[r]*wp[r];
    dt[(size_t)rowid*512 + dd] = softplusf(s);
  }
}

// M5a: chunked scan pass A
__global__ void m5_passA(const float* __restrict__ dt, const float* __restrict__ xc,
                         const float* __restrict__ dbl, const float* __restrict__ Alog,
                         float* __restrict__ P, float* __restrict__ Hl){
  int bx = blockIdx.x;
  int seg = bx & 7, half = (bx>>3)&1, rb = bx>>4;
  int dd = half*256 + threadIdx.x;
  int d = (rb>>3)&1;
  float A[16], h[16], pr[16];
  #pragma unroll
  for(int s=0;s<16;s++){
    A[s] = -__expf(Alog[(size_t)(d*512 + dd)*16 + s]);
    h[s] = 0.f; pr[s] = 1.f;
  }
  int l0 = seg*16;
  for(int l=l0;l<l0+16;l++){
    size_t row = (size_t)rb*128 + l;
    float dtv = dt[row*512 + dd];
    float xcv = xc[row*512 + dd];
    float bx_ = dtv*xcv;
    const float* dr = dbl + row*48;
    #pragma unroll
    for(int s=0;s<16;s++){
      float dA = __expf(dtv*A[s]);
      pr[s] *= dA;
      h[s] = dA*h[s] + bx_*dr[16+s];
    }
  }
  size_t o = ((size_t)(rb*8 + seg)*512 + dd)*16;
  #pragma unroll
  for(int s=0;s<16;s+=4){
    *(f32x4_t*)(P  + o + s) = (f32x4_t){pr[s],pr[s+1],pr[s+2],pr[s+3]};
    *(f32x4_t*)(Hl + o + s) = (f32x4_t){h[s],h[s+1],h[s+2],h[s+3]};
  }
}

// M5b: combine prefix, re-scan, emit y
__global__ void m5_passB(const float* __restrict__ dt, const float* __restrict__ xc,
                         const float* __restrict__ dbl, const float* __restrict__ xz,
                         const float* __restrict__ Alog, const float* __restrict__ Dp,
                         const float* __restrict__ P, const float* __restrict__ Hl,
                         bf16* __restrict__ ybb){
  int bx = blockIdx.x;
  int seg = bx & 7, half = (bx>>3)&1, rb = bx>>4;
  int dd = half*256 + threadIdx.x;
  int d = (rb>>3)&1;
  float A[16], h[16];
  #pragma unroll
  for(int s=0;s<16;s++){
    A[s] = -__expf(Alog[(size_t)(d*512 + dd)*16 + s]);
    h[s] = 0.f;
  }
  for(int j=0;j<seg;j++){
    size_t o = ((size_t)(rb*8 + j)*512 + dd)*16;
    #pragma unroll
    for(int s=0;s<16;s+=4){
      f32x4_t pv = *(const f32x4_t*)(P + o + s);
      f32x4_t hv = *(const f32x4_t*)(Hl + o + s);
      h[s]   = pv[0]*h[s]   + hv[0];
      h[s+1] = pv[1]*h[s+1] + hv[1];
      h[s+2] = pv[2]*h[s+2] + hv[2];
      h[s+3] = pv[3]*h[s+3] + hv[3];
    }
  }
  float Dv = Dp[d*512 + dd];
  int l0 = seg*16;
  for(int l=l0;l<l0+16;l++){
    size_t row = (size_t)rb*128 + l;
    float dtv = dt[row*512 + dd];
    float xcv = xc[row*512 + dd];
    float zgv = xz[row*1024 + 512 + dd];
    const float* dr = dbl + row*48;
    float bx_ = dtv*xcv;
    float y = 0.f;
    #pragma unroll
    for(int s=0;s<16;s++){
      h[s] = __expf(dtv*A[s])*h[s] + bx_*dr[16+s];
      y += h[s]*dr[32+s];
    }
    ybb[row*512 + dd] = f2bf((y + xcv*Dv) * siluf(zgv));
  }
}

// M6 (MFMA) + fused row-LN
__global__ __launch_bounds__(256,2)
void m6_mfma(const bf16* __restrict__ ybb, const bf16* __restrict__ Wout,
             const float* __restrict__ lng, const float* __restrict__ lnb,
             float* __restrict__ mo){
  __shared__ char smem[64*264*4];
  bf16* ybt = (bf16*)smem;
  float* fbuf = (float*)smem;
  int bx = blockIdx.x;
  int lt = bx & 1, b = (bx>>1)&7, r = bx>>4;
  int d = r & 1, rb = r*8 + b;
  size_t rowbase = (size_t)rb*128 + lt*64;
  int t = threadIdx.x;
  for(int i=t;i<4096;i+=256){
    int row = i>>6, c8 = (i&63)*8;
    short8_t v = *(const short8_t*)((const short*)ybb + (rowbase + row)*512 + c8);
    *(short8_t*)&ybt[row*520 + c8] = v;
  }
  __syncthreads();
  int wv = t>>6, lane = t&63, quad = lane>>4, l16 = lane&15;
  int m0 = wv*64;
  f32x4_t acc[4][4];
  #pragma unroll
  for(int ms=0;ms<4;ms++)
    #pragma unroll
    for(int ns=0;ns<4;ns++) acc[ms][ns] = (f32x4_t){0.f,0.f,0.f,0.f};
  const short* wbase = (const short*)Wout + (size_t)d*256*512;
  for(int k0=0;k0<512;k0+=32){
    short8_t afr[4], bfr[4];
    #pragma unroll
    for(int ms=0;ms<4;ms++)
      afr[ms] = *(const short8_t*)(wbase + (size_t)(m0 + ms*16 + l16)*512 + k0 + quad*8);
    #pragma unroll
    for(int ns=0;ns<4;ns++)
      bfr[ns] = *(const short8_t*)&ybt[(ns*16 + l16)*520 + k0 + quad*8];
    #pragma unroll
    for(int ms=0;ms<4;ms++)
      #pragma unroll
      for(int ns=0;ns<4;ns++)
        acc[ms][ns] = __builtin_amdgcn_mfma_f32_16x16x32_bf16(afr[ms], bfr[ns], acc[ms][ns], 0,0,0);
  }
  __syncthreads();
  #pragma unroll
  for(int ns=0;ns<4;ns++){
    int row = ns*16 + l16;
    #pragma unroll
    for(int ms=0;ms<4;ms++){
      int o = m0 + ms*16 + quad*4;
      *(f32x4_t*)(fbuf + row*264 + o) = acc[ms][ns];
    }
  }
  __syncthreads();
  {
    int row = t >> 2, part = t & 3;
    const float* fr = fbuf + row*264;
    float s = 0.f;
    #pragma unroll 8
    for(int j=0;j<64;j++){
      int col = part*64 + ((j + part*16) & 63);
      s += fr[col];
    }
    s += __shfl_xor(s, 1, 64);
    s += __shfl_xor(s, 2, 64);
    float m = s * (1.f/256.f);
    float q = 0.f;
    #pragma unroll 8
    for(int j=0;j<64;j++){
      int col = part*64 + ((j + part*16) & 63);
      float dv = fr[col] - m;
      q += dv*dv;
    }
    q += __shfl_xor(q, 1, 64);
    q += __shfl_xor(q, 2, 64);
    float rs = rsqrtf(q*(1.f/256.f) + EPSV);
    float* dst = mo + (rowbase + row)*256;
    for(int j=0;j<64;j++){
      int col = part*64 + j;
      dst[col] = (fr[col] - m)*rs*lng[col] + lnb[col];
    }
  }
}

// M7 + fused row-LN on outputs
__global__ void m7_proj(const float* __restrict__ mo, const float* __restrict__ PT,
                        const float* __restrict__ pb, const float* __restrict__ lng,
                        const float* __restrict__ lnb, float* __restrict__ resm,
                        float* __restrict__ resn){
  __shared__ float ct[16*512];
  __shared__ float fbuf[16*264];
  int bx = blockIdx.x;
  int tt = bx >> 6, rem = bx & 63, b = rem >> 3, lt = rem & 7;
  int fr_ = tt*2, br = tt*2 + 1;
  for(int i=threadIdx.x;i<16*512;i+=256){
    int lr = i >> 9, k = i & 511;
    int l = lt*16 + lr;
    ct[i] = (k < 256)
      ? mo[(((size_t)(fr_*8+b)*128) + l)*256 + k]
      : mo[(((size_t)(br*8+b)*128) + (127-l))*256 + (k-256)];
  }
  __syncthreads();
  float acc[16];
  #pragma unroll
  for(int q=0;q<16;q++) acc[q] = 0.f;
  int t = threadIdx.x;
  for(int k=0;k<512;k++){
    float pv = PT[(size_t)k*256 + t];
    #pragma unroll
    for(int q=0;q<16;q++) acc[q] += pv * ct[(q<<9) + k];
  }
  float bias = pb[t];
  #pragma unroll
  for(int q=0;q<16;q++) fbuf[q*264 + t] = acc[q] + bias;
  __syncthreads();
  float* dstbuf = tt ? resn : resm;
  if(t < 64){
    int row = t >> 2, part = t & 3;
    const float* fr = fbuf + row*264;
    float s = 0.f;
    for(int j=0;j<64;j++){
      int col = part*64 + ((j + part*16) & 63);
      s += fr[col];
    }
    s += __shfl_xor(s, 1, 64);
    s += __shfl_xor(s, 2, 64);
    float m = s * (1.f/256.f);
    float q = 0.f;
    for(int j=0;j<64;j++){
      int col = part*64 + ((j + part*16) & 63);
      float dv = fr[col] - m;
      q += dv*dv;
    }
    q += __shfl_xor(q, 1, 64);
    q += __shfl_xor(q, 2, 64);
    float rs = rsqrtf(q*(1.f/256.f) + EPSV);
    float* dst = dstbuf + ((size_t)b*128 + lt*16 + row)*256;
    for(int j=0;j<64;j++){
      int col = part*64 + j;
      dst[col] = (fr[col] - m)*rs*lng[col] + lnb[col];
    }
  }
}

// K1: stride-2 transposed depthwise 3x3 + BN + ReLU -> zT (pixel-major bf16)
__global__ __launch_bounds__(256)
void k1_deconv_T(const float* __restrict__ x, const float* __restrict__ wdw,
                 const float* __restrict__ g1, const float* __restrict__ b1,
                 bf16* __restrict__ zT){
  __shared__ float in[2*64*33];
  __shared__ bf16 ot[64*80];
  int bx = blockIdx.x;
  int cb = bx & 3, half = (bx>>2)&1, h = (bx>>3)&127, b = bx>>10;
  int c0 = cb*64, w0 = half*64, iw0 = w0>>1;
  int h_odd = h & 1;
  int ihA = h_odd ? (h-1)>>1 : h>>1;
  int ihB = (h+1)>>1;
  bool hasB = h_odd && (ihB < 64);
  for(int i = threadIdx.x; i < 4224; i += 256){
    int row = i / 2112;
    int rem = i - row*2112;
    int c = rem / 33;
    int iw = rem - c*33;
    int ihl = row ? ihB : ihA;
    bool valid = (iw0 + iw < 64) && (row == 0 || hasB);
    in[i] = valid ? x[(((size_t)b*256 + c0 + c)<<12) + (ihl<<6) + iw0 + iw] : 0.f;
  }
  __syncthreads();
  int c = threadIdx.x & 63, g = threadIdx.x >> 6;
  const float* wp = wdw + (c0+c)*9;
  int khA3 = h_odd ? 6 : 3;
  float wA0 = wp[khA3], wA1 = wp[khA3+1], wA2 = wp[khA3+2];
  float wB0 = wp[0],    wB1 = wp[1],      wB2 = wp[2];
  float scale = g1[c0+c]*BNSC, bias = b1[c0+c];
  const float* inA = in + c*33;
  const float* inB = in + 2112 + c*33;
  #pragma unroll
  for(int i=0;i<16;i++){
    int wi = g*16 + i;
    float s;
    if(!(i&1)){
      int iw = wi>>1;
      s = inA[iw]*wA1 + inB[iw]*wB1;
    } else {
      int iwa = (wi-1)>>1, iwb = (wi+1)>>1;
      s = inA[iwa]*wA2 + inA[iwb]*wA0 + inB[iwa]*wB2 + inB[iwb]*wB0;
    }
    ot[wi*80 + c] = f2bf(fmaxf(s*scale + bias, 0.f));
  }
  __syncthreads();
  int rr = threadIdx.x >> 3;
  int co = (threadIdx.x & 7) * 8;
  size_t obase = (((size_t)b*16384) + (size_t)h*128 + w0)*256 + c0;
  #pragma unroll
  for(int pass=0; pass<2; pass++){
    int wi = rr + pass*32;
    short8_t v = *(const short8_t*)&ot[wi*80 + co];
    *(short8_t*)((short*)zT + obase + (size_t)wi*256 + co) = v;
  }
}

// K2 (MFMA): 128 px x 256 out, K=256, prefetch weights, LDS-staged coalesced writes
__global__ __launch_bounds__(256,2)
void k2_mfma(const bf16* __restrict__ zT, const bf16* __restrict__ Wub,
             const float* __restrict__ g2, const float* __restrict__ b2,
             const float* __restrict__ resm, const float* __restrict__ resn,
             bf16* __restrict__ resT){
  __shared__ bf16 zt[128*264];
  int b = blockIdx.y;
  int p0 = blockIdx.x*128;
  int t = threadIdx.x;
  {
    const short* src = (const short*)zT + (((size_t)b*16384 + p0)*256);
    int pr = t>>5;
    int cc = (t&31)*8;
    #pragma unroll
    for(int i=0;i<16;i++){
      int p = pr + i*8;
      short8_t v = *(const short8_t*)(src + (size_t)p*256 + cc);
      *(short8_t*)&zt[p*264 + cc] = v;
    }
  }
  __syncthreads();
  int wv = t>>6, lane = t&63, quad = lane>>4, l16 = lane&15;
  int m0 = wv*64;
  f32x4_t acc[4][8];
  #pragma unroll
  for(int ms=0;ms<4;ms++)
    #pragma unroll
    for(int ns=0;ns<8;ns++) acc[ms][ns] = (f32x4_t){0.f,0.f,0.f,0.f};
  const short* wp = (const short*)Wub + (size_t)(m0 + l16)*256 + quad*8;
  short8_t afr[4];
  #pragma unroll
  for(int ms=0;ms<4;ms++) afr[ms] = *(const short8_t*)(wp + (size_t)ms*16*256);
  for(int k0=0;k0<256;k0+=32){
    short8_t anext[4];
    if(k0 + 32 < 256){
      #pragma unroll
      for(int ms=0;ms<4;ms++)
        anext[ms] = *(const short8_t*)(wp + (size_t)ms*16*256 + k0 + 32);
    }
    short8_t bfr[8];
    #pragma unroll
    for(int ns=0;ns<8;ns++)
      bfr[ns] = *(const short8_t*)&zt[(ns*16 + l16)*264 + k0 + quad*8];
    #pragma unroll
    for(int ms=0;ms<4;ms++)
      #pragma unroll
      for(int ns=0;ns<8;ns++)
        acc[ms][ns] = __builtin_amdgcn_mfma_f32_16x16x32_bf16(afr[ms], bfr[ns], acc[ms][ns], 0,0,0);
    #pragma unroll
    for(int ms=0;ms<4;ms++) afr[ms] = anext[ms];
  }
  __syncthreads();   // all waves done reading zt; reuse as output staging tile
  #pragma unroll
  for(int ns=0;ns<8;ns++){
    int pl = ns*16 + l16;            // local pixel 0..127
    int p = p0 + pl;
    int hh = p>>7, ww = p&127;
    const float* rm = resm + ((size_t)b*128+hh)*256;
    const float* rn = resn + ((size_t)b*128+ww)*256;
    #pragma unroll
    for(int ms=0;ms<4;ms++){
      int o = m0 + ms*16 + quad*4;
      f32x4_t a = acc[ms][ns];
      f32x4_t gv = *(const f32x4_t*)(g2+o);
      f32x4_t bv = *(const f32x4_t*)(b2+o);
      f32x4_t rmv = *(const f32x4_t*)(rm+o);
      f32x4_t rnv = *(const f32x4_t*)(rn+o);
      alignas(8) bf16 ov[4];
      #pragma unroll
      for(int r=0;r<4;r++){
        float zv = a[r]*(gv[r]*BNSC) + bv[r];
        zv = fminf(fmaxf(zv, 0.f), 6.f);
        float gate = fminf(fmaxf(rmv[r]+rnv[r]+3.f, 0.f), 6.f)*(1.f/6.f);
        ov[r] = f2bf(zv*gate);
      }
      *(short4_t*)&zt[pl*264 + o] = *(const short4_t*)ov;
    }
  }
  __syncthreads();
  // stream out: 128 rows x 512 B, fully coalesced (32 lanes x 16 B per row)
  {
    short* dst = (short*)resT + ((size_t)b*16384 + p0)*256;
    int slot0 = t;                    // 4096 slots total (128 rows x 32)
    #pragma unroll
    for(int it=0; it<16; it++){
      int slot = slot0 + it*256;
      int row = slot >> 5;
      int co = (slot & 31)*8;
      short8_t v = *(const short8_t*)&zt[row*264 + co];
      *(short8_t*)(dst + (size_t)row*256 + co) = v;
    }
  }
}

// GN1 stats over pixel-major resT (separate pass)
__global__ void gn_stats_pm(const bf16* __restrict__ resT, float* __restrict__ sum,
                            float* __restrict__ ssq){
  __shared__ float ls[256], lq[256];
  int b = blockIdx.y, p0 = blockIdx.x*256;
  int c = threadIdx.x;
  const short* src = (const short*)resT + ((size_t)b*16384 + p0)*256 + c;
  float s=0.f, q=0.f;
  for(int i=0;i<256;i++){
    bf16 raw; *(short*)&raw = src[(size_t)i*256];
    float v = bf2f(raw);
    s += v; q += v*v;
  }
  ls[c]=s; lq[c]=q;
  __syncthreads();
  if(c<32){
    float S=0.f,Q=0.f;
    #pragma unroll
    for(int j=0;j<8;j++){ S+=ls[c*8+j]; Q+=lq[c*8+j]; }
    atomicAdd(&sum[b*32+c], S);
    atomicAdd(&ssq[b*32+c], Q);
  }
}

// K4 (MFMA): inline GN1 finalize, 128-px tile, weight prefetch, GN2 stats via shfl
__global__ __launch_bounds__(256,2)
void k4_mfma(const bf16* __restrict__ resT, const bf16* __restrict__ Wdb,
             const float* __restrict__ gsum1, const float* __restrict__ gssq1,
             const float* __restrict__ gng, const float* __restrict__ gnb,
             const float* __restrict__ dbg, const float* __restrict__ dbb,
             float* __restrict__ t1, float* __restrict__ gsum2, float* __restrict__ gssq2){
  __shared__ bf16 at[128*264];
  __shared__ float sc[256], sb[256];
  __shared__ float stm[32], str[32];
  int b = blockIdx.y;
  int q0 = blockIdx.x*128;
  int t = threadIdx.x;
  if(t < 32){
    float m = gsum1[b*32+t] * (1.f/131072.f);
    float var = gssq1[b*32+t] * (1.f/131072.f) - m*m;
    stm[t] = m;
    str[t] = rsqrtf(var + EPSV);
  }
  __syncthreads();
  {
    int cch = t, g = cch>>3;
    float m = stm[g], rs = str[g];
    float s = rs*gng[cch];
    sc[cch] = s; sb[cch] = gnb[cch] - m*s;
  }
  __syncthreads();
  {
    int pr = t>>5;
    int cc = (t&31)*8;
    #pragma unroll
    for(int i=0;i<16;i++){
      int q = pr + i*8;
      int qq = q0 + q;
      int y = qq>>6, xw = qq&63;
      size_t srow = ((size_t)b*16384 + (size_t)y*256 + xw*2)*256;
      short8_t v = *(const short8_t*)((const short*)resT + srow + cc);
      const bf16* vv = (const bf16*)&v;
      alignas(16) bf16 ov[8];
      #pragma unroll
      for(int j=0;j<8;j++) ov[j] = f2bf(bf2f(vv[j])*sc[cc+j] + sb[cc+j]);
      *(short8_t*)&at[q*264 + cc] = *(const short8_t*)ov;
    }
  }
  __syncthreads();
  int wv = t>>6, lane = t&63, quad = lane>>4, l16 = lane&15;
  int n0 = wv*64;
  f32x4_t acc[8][4];
  #pragma unroll
  for(int ms=0;ms<8;ms++)
    #pragma unroll
    for(int ns=0;ns<4;ns++) acc[ms][ns] = (f32x4_t){0.f,0.f,0.f,0.f};
  const short* wp = (const short*)Wdb + (size_t)(n0 + l16)*256 + quad*8;
  short8_t bfr[4];
  #pragma unroll
  for(int ns=0;ns<4;ns++) bfr[ns] = *(const short8_t*)(wp + (size_t)ns*16*256);
  for(int k0=0;k0<256;k0+=32){
    short8_t bnext[4];
    if(k0 + 32 < 256){
      #pragma unroll
      for(int ns=0;ns<4;ns++)
        bnext[ns] = *(const short8_t*)(wp + (size_t)ns*16*256 + k0 + 32);
    }
    short8_t afr[8];
    #pragma unroll
    for(int ms=0;ms<8;ms++)
      afr[ms] = *(const short8_t*)&at[(ms*16 + l16)*264 + k0 + quad*8];
    #pragma unroll
    for(int ms=0;ms<8;ms++)
      #pragma unroll
      for(int ns=0;ns<4;ns++)
        acc[ms][ns] = __builtin_amdgcn_mfma_f32_16x16x32_bf16(afr[ms], bfr[ns], acc[ms][ns], 0,0,0);
    #pragma unroll
    for(int ns=0;ns<4;ns++) bfr[ns] = bnext[ns];
  }
  #pragma unroll
  for(int ns=0;ns<4;ns++){
    int o = n0 + ns*16 + l16;
    float s2 = dbg[o]*BNSC, bb2 = dbb[o];
    float* dst = t1 + (((size_t)b*256 + o) << 12);
    float s_=0.f, q_=0.f;
    #pragma unroll
    for(int ms=0;ms<8;ms++){
      int ps = q0 + ms*16 + quad*4;
      f32x4_t a = acc[ms][ns];
      f32x4_t ov;
      #pragma unroll
      for(int r=0;r<4;r++){
        ov[r] = a[r]*s2 + bb2;
        s_ += ov[r];
        q_ += ov[r]*ov[r];
      }
      *(f32x4_t*)(dst + ps) = ov;
    }
    #pragma unroll
    for(int msk=1; msk<=4; msk<<=1){
      s_ += __shfl_xor(s_, msk, 64);
      q_ += __shfl_xor(q_, msk, 64);
    }
    s_ += __shfl_xor(s_, 16, 64);
    q_ += __shfl_xor(q_, 16, 64);
    s_ += __shfl_xor(s_, 32, 64);
    q_ += __shfl_xor(q_, 32, 64);
    if(((l16 & 7) == 0) && (quad == 0)){
      atomicAdd(&gsum2[b*32 + (o>>3)], s_);
      atomicAdd(&gssq2[b*32 + (o>>3)], q_);
    }
  }
}

// K6 (float4): t1 = gn2(t1) + x, + GN3 partials
__global__ void k6_gn_add(float* __restrict__ t1, const float* __restrict__ x,
                          const float* __restrict__ gsum2, const float* __restrict__ gssq2,
                          const float* __restrict__ gng, const float* __restrict__ gnb,
                          float* __restrict__ gsum3, float* __restrict__ gssq3){
  __shared__ float sm[8];
  int i4 = blockIdx.x*256 + threadIdx.x;
  int idx = i4 << 2;
  int c = (idx >> 12) & 255, b = idx >> 20, g = c >> 3;
  float m2 = gsum2[b*32+g] * (1.f/32768.f);
  float var = gssq2[b*32+g] * (1.f/32768.f) - m2*m2;
  float rs = rsqrtf(var + EPSV);
  float scl = rs*gng[c], off = gnb[c] - m2*scl;
  f32x4_t tv = *(const f32x4_t*)(t1 + idx);
  f32x4_t xv = *(const f32x4_t*)(x + idx);
  f32x4_t ov;
  float S = 0.f, Q = 0.f;
  #pragma unroll
  for(int r=0;r<4;r++){
    float v = tv[r]*scl + off + xv[r];
    ov[r] = v;
    S += v; Q += v*v;
  }
  *(f32x4_t*)(t1 + idx) = ov;
  S = blk_sum(S, sm);
  Q = blk_sum(Q, sm);
  if(threadIdx.x == 0){
    atomicAdd(&gsum3[b*32 + g], S);
    atomicAdd(&gssq3[b*32 + g], Q);
  }
}

// K8 (float4): out = gn3(t1)
__global__ void k8_gn_out(const float* __restrict__ t1, const float* __restrict__ gsum3,
                          const float* __restrict__ gssq3, const float* __restrict__ gng,
                          const float* __restrict__ gnb, float* __restrict__ out){
  int i4 = blockIdx.x*256 + threadIdx.x;
  int idx = i4 << 2;
  int c = (idx >> 12) & 255, b = idx >> 20, g = c >> 3;
  float m = gsum3[b*32+g] * (1.f/32768.f);
  float var = gssq3[b*32+g] * (1.f/32768.f) - m*m;
  float rs = rsqrtf(var + EPSV);
  float scl = rs*gng[c], off = gnb[c] - m*scl;
  f32x4_t tv = *(const f32x4_t*)(t1 + idx);
  f32x4_t ov;
  #pragma unroll
  for(int r=0;r<4;r++) ov[r] = tv[r]*scl + off;
  *(f32x4_t*)(out + idx) = ov;
}

extern "C" void kernel_launch(void* const* d_in, const int* in_sizes, int n_in,
                              void* d_out, int out_size, void* d_ws, size_t ws_size,
                              hipStream_t stream){
  const float* x      = (const float*)d_in[0];
  const float* pos    = (const float*)d_in[1];
  const float* ln_g   = (const float*)d_in[2];
  const float* ln_b   = (const float*)d_in[3];
  const float* in_w   = (const float*)d_in[4];
  const float* conv_w = (const float*)d_in[5];
  const float* conv_b = (const float*)d_in[6];
  const float* xproj  = (const float*)d_in[7];
  const float* dt_w   = (const float*)d_in[8];
  const float* dt_b   = (const float*)d_in[9];
  const float* A_log  = (const float*)d_in[10];
  const float* Dp     = (const float*)d_in[11];
  const float* out_w  = (const float*)d_in[12];
  const float* proj_w = (const float*)d_in[13];
  const float* proj_b = (const float*)d_in[14];
  const float* dw_w   = (const float*)d_in[15];
  const float* bn1g   = (const float*)d_in[16];
  const float* bn1b   = (const float*)d_in[17];
  const float* pw_w   = (const float*)d_in[18];
  const float* bn2g   = (const float*)d_in[19];
  const float* bn2b   = (const float*)d_in[20];
  const float* dpw_w  = (const float*)d_in[21];
  const float* dbng   = (const float*)d_in[22];
  const float* dbnb   = (const float*)d_in[23];
  const float* gng    = (const float*)d_in[24];
  const float* gnb    = (const float*)d_in[25];
  float* out = (float*)d_out;

  float* ws = (float*)d_ws;
  bf16*  resT = (bf16*)ws;                       // pixel-major (b,p,c), 64MB
  bf16*  zT   = (bf16*)(ws + 16777216);          // pixel-major (b,p,c), 64MB
  float* scanP = ws + 16777216;                  // overlay of zT region
  float* scanH = ws + 16777216 + 2097152;
  float* zone = ws + 33554432;
  float* xz   = zone;                            // 4,194,304
  float* xc   = xz  + 4194304;                   // 2,097,152
  float* dbl  = xc  + 2097152;                   //   196,608
  float* dtb  = dbl + 196608;                    // 2,097,152
  bf16*  ybb  = (bf16*)(dtb + 2097152);          // 1,048,576 f worth
  float* t1   = zone;                            // overlay (first 8,388,608)
  float* mo   = zone + 9633792;                  // 1,048,576
  float* resm = mo   + 1048576;
  float* resn = resm + 262144;
  float* pmax = resn + 262144;
  float* pmin = pmax + 262144;
  float* PT   = pmin + 262144;
  bf16*  ubmax= (bf16*)(PT + 131072);
  bf16*  ubmin= (bf16*)(PT + 131072 + 131072);
  bf16*  Winb = (bf16*)(PT + 131072 + 262144);
  bf16*  Woutb= (bf16*)(PT + 131072 + 524288);
  bf16*  Wub  = (bf16*)(PT + 131072 + 655360);
  bf16*  Wdb  = (bf16*)(PT + 131072 + 688128);
  float* gacc = PT + 131072 + 720896;
  float* gsum1 = gacc,        *gssq1 = gacc + 256;
  float* gsum2 = gacc + 512,  *gssq2 = gacc + 768;
  float* gsum3 = gacc + 1024, *gssq3 = gacc + 1280;

  prep_weights<<<4096,256,0,stream>>>(in_w, out_w, pw_w, dpw_w, proj_w,
                                      Winb, Woutb, Wub, Wdb, PT, gacc);

  r1_reduce_pe<<<2048,256,0,stream>>>(x, pos, pmax, pmin);
  ln_rows2<<<2048,256,0,stream>>>(pmax, pmin, ln_g, ln_b, ubmax, ubmin);

  m1_mfma<<<256,256,0,stream>>>(ubmax, ubmin, Winb, xz);
  m234<<<4096,256,0,stream>>>(xz, conv_w, conv_b, xproj, dt_w, dt_b, xc, dbl, dtb);
  m5_passA<<<512,256,0,stream>>>(dtb, xc, dbl, A_log, scanP, scanH);
  m5_passB<<<512,256,0,stream>>>(dtb, xc, dbl, xz, A_log, Dp, scanP, scanH, ybb);
  m6_mfma<<<64,256,0,stream>>>(ybb, Woutb, ln_g, ln_b, mo);
  m7_proj<<<128,256,0,stream>>>(mo, PT, proj_b, ln_g, ln_b, resm, resn);

  k1_deconv_T<<<8192,256,0,stream>>>(x, dw_w, bn1g, bn1b, zT);
  k2_mfma<<<dim3(128,8),256,0,stream>>>(zT, Wub, bn2g, bn2b, resm, resn, resT);
  gn_stats_pm<<<dim3(64,8),256,0,stream>>>(resT, gsum1, gssq1);

  k4_mfma<<<dim3(32,8),256,0,stream>>>(resT, Wdb, gsum1, gssq1,
                                       gng, gnb, dbng, dbnb, t1, gsum2, gssq2);

  k6_gn_add<<<8192,256,0,stream>>>(t1, x, gsum2, gssq2, gng, gnb, gsum3, gssq3);
  k8_gn_out<<<8192,256,0,stream>>>(t1, gsum3, gssq3, gng, gnb, out);
}